// Round 18
// baseline (467.877 us; speedup 1.0000x reference)
//
#include <hip/hip_runtime.h>
#include <stdint.h>

typedef unsigned short u16;
typedef __attribute__((ext_vector_type(8))) short bf8v;    // 8 bf16 MFMA frag
typedef __attribute__((ext_vector_type(4))) float f32x4;   // C/D frag

#define NB   128
#define NP   512
#define KNN  16
#define CH   64
#define NPB  8                       // points per group
#define GPH  (NB * NP / NPB)         // 8192 groups per phase
#define GRID_MLP 4096                // blocks per phase (2 groups in flight, no loop)
#define GPB  2                       // groups per block
#define SLOTS 512

// ---------------- workspace layout (bytes) ----------------
#define OFF_IDX   0                  // 4 MB
#define OFF_PART  0x400000           // 1 MB: [L][slot][sum/ssq][ch]
#define PART_BYTES (4 * SLOTS * 2 * 64 * 4)
#define OFF_BN    0x500000           // 2 KB
#define OFF_WN    0x500800           // 8 KB bf16 [o][c]
#define OFF_WC    0x502800
#define OFF_W1B   0x504800
#define OFF_W2B   0x506800
#define OFF_SCWB  0x508800
#define OFF_FB16  0x600000           // 8.4 MB bf16 feats [n*NP+p][64]
#define OFF_Y1    0x1000000          // 134 MB bf16 y frags [group][tid][32]
#define Y1_BYTES  ((size_t)GPH * 256 * 32 * 2)

__device__ __forceinline__ u16 f2bf(float f) {
    union { float f; unsigned u; } v; v.f = f;
    unsigned r = v.u + 0x7fffu + ((v.u >> 16) & 1u);       // RNE
    return (u16)(r >> 16);
}
__device__ __forceinline__ float bf2f(u16 b) {
    union { unsigned u; float f; } v; v.u = ((unsigned)b) << 16;
    return v.f;
}
struct alignas(16) US8 { u16 v[8]; };
__device__ __forceinline__ US8 pack8(float4 f0, float4 f1) {
    US8 u;
    u.v[0]=f2bf(f0.x); u.v[1]=f2bf(f0.y); u.v[2]=f2bf(f0.z); u.v[3]=f2bf(f0.w);
    u.v[4]=f2bf(f1.x); u.v[5]=f2bf(f1.y); u.v[6]=f2bf(f1.z); u.v[7]=f2bf(f1.w);
    return u;
}

// ---------------- weight prep ----------------
__global__ void prep_weights(const float* __restrict__ W0, const float* __restrict__ W1,
                             const float* __restrict__ W2, const float* __restrict__ scW,
                             u16* Wn, u16* Wc, u16* W1b, u16* W2b, u16* scWb) {
    int i = blockIdx.x * 256 + threadIdx.x;                // i = o*64 + c
    if (i < 4096) {
        int o = i >> 6, c = i & 63;
        float a = W0[o * 128 + c], b = W0[o * 128 + 64 + c];
        Wc[i] = f2bf(a - b);
        Wn[i] = f2bf(b);
        W1b[i]  = f2bf(W1[i]);
        W2b[i]  = f2bf(W2[i]);
        scWb[i] = f2bf(scW[i]);
    }
}

__global__ void feats_to_bf16(const float* __restrict__ feats, u16* __restrict__ fb16) {
    size_t i = ((size_t)blockIdx.x * 256 + threadIdx.x) * 8;
    float4 f0 = *(const float4*)(feats + i);
    float4 f1 = *(const float4*)(feats + i + 4);
    *(US8*)(fb16 + i) = pack8(f0, f1);
}

// u32 split-key stable insert (R16, verified): candidates arrive in ascending
// q, so strict-< stable insertion on the monotone-transformed distance alone
// reproduces (d,q) lexicographic order exactly.
#define INS32(ub, qq) do { if ((ub) < d16) {                                  \
    bool c00=(ub)<d00, c01=(ub)<d01, c02=(ub)<d02, c03=(ub)<d03,              \
         c04=(ub)<d04, c05=(ub)<d05, c06=(ub)<d06, c07=(ub)<d07,              \
         c08=(ub)<d08, c09=(ub)<d09, c10=(ub)<d10, c11=(ub)<d11,              \
         c12=(ub)<d12, c13=(ub)<d13, c14=(ub)<d14, c15=(ub)<d15;              \
    d16 = c15 ? d15 : (ub);                 i16 = c15 ? i15 : (qq);           \
    d15 = c14 ? d14 : (c15 ? (ub) : d15);   i15 = c14 ? i14 : (c15 ? (qq) : i15); \
    d14 = c13 ? d13 : (c14 ? (ub) : d14);   i14 = c13 ? i13 : (c14 ? (qq) : i14); \
    d13 = c12 ? d12 : (c13 ? (ub) : d13);   i13 = c12 ? i12 : (c13 ? (qq) : i13); \
    d12 = c11 ? d11 : (c12 ? (ub) : d12);   i12 = c11 ? i11 : (c12 ? (qq) : i12); \
    d11 = c10 ? d10 : (c11 ? (ub) : d11);   i11 = c10 ? i10 : (c11 ? (qq) : i11); \
    d10 = c09 ? d09 : (c10 ? (ub) : d10);   i10 = c09 ? i09 : (c10 ? (qq) : i10); \
    d09 = c08 ? d08 : (c09 ? (ub) : d09);   i09 = c08 ? i08 : (c09 ? (qq) : i09); \
    d08 = c07 ? d07 : (c08 ? (ub) : d08);   i08 = c07 ? i07 : (c08 ? (qq) : i08); \
    d07 = c06 ? d06 : (c07 ? (ub) : d07);   i07 = c06 ? i06 : (c07 ? (qq) : i07); \
    d06 = c05 ? d05 : (c06 ? (ub) : d06);   i06 = c05 ? i05 : (c06 ? (qq) : i06); \
    d05 = c04 ? d04 : (c05 ? (ub) : d05);   i05 = c04 ? i04 : (c05 ? (qq) : i05); \
    d04 = c03 ? d03 : (c04 ? (ub) : d04);   i04 = c03 ? i03 : (c04 ? (qq) : i04); \
    d03 = c02 ? d02 : (c03 ? (ub) : d03);   i03 = c02 ? i02 : (c03 ? (qq) : i03); \
    d02 = c01 ? d01 : (c02 ? (ub) : d02);   i02 = c01 ? i01 : (c02 ? (qq) : i02); \
    d01 = c00 ? d00 : (c01 ? (ub) : d01);   i01 = c00 ? i00 : (c01 ? (qq) : i01); \
    d00 = c00 ? (ub) : d00;                 i00 = c00 ? (qq) : i00;           \
} } while (0)

// ---------------- KNN (R16 form — best measured: 132 us; CLOSED) ----------
__global__ __launch_bounds__(256)
void knn_kernel(const float* __restrict__ pts, int* __restrict__ idx) {
#pragma clang fp contract(off)
    __shared__ __align__(16) float4 sp[NP];
    const int tid = threadIdx.x;
    const int n = blockIdx.x >> 1;
    const float* pb = pts + (size_t)n * NP * 2;
    for (int i = tid; i < NP; i += 256) {
        float x = pb[i * 2], y = pb[i * 2 + 1];
        float r = x * x + y * y;                  // matches np: mul, mul, add
        sp[i] = make_float4(x, y, r, 0.f);
    }
    __syncthreads();
    const int p = ((blockIdx.x & 1) << 8) + tid;
    const float xp = sp[p].x, yp = sp[p].y, rp = sp[p].z;

    unsigned d00=~0u,d01=~0u,d02=~0u,d03=~0u,d04=~0u,d05=~0u,d06=~0u,d07=~0u,
             d08=~0u,d09=~0u,d10=~0u,d11=~0u,d12=~0u,d13=~0u,d14=~0u,d15=~0u,
             d16=~0u;
    unsigned i00=0,i01=0,i02=0,i03=0,i04=0,i05=0,i06=0,i07=0,
             i08=0,i09=0,i10=0,i11=0,i12=0,i13=0,i14=0,i15=0,i16=0;

    for (int q = 0; q < NP; ++q) {
        float4 sq = sp[q];
        float m = xp * sq.x + yp * sq.y;          // einsum inner order
        float d = (rp - 2.0f * m) + sq.z;         // (r - 2m) + r^T order
        unsigned int ub = __float_as_uint(d);
        ub = (ub & 0x80000000u) ? ~ub : (ub | 0x80000000u);
        INS32(ub, (unsigned)q);
    }
    int* ob = idx + ((size_t)n * NP + p) * KNN;   // drop slot 0 (self)
    ob[ 0] = (int)i01;  ob[ 1] = (int)i02;  ob[ 2] = (int)i03;  ob[ 3] = (int)i04;
    ob[ 4] = (int)i05;  ob[ 5] = (int)i06;  ob[ 6] = (int)i07;  ob[ 7] = (int)i08;
    ob[ 8] = (int)i09;  ob[ 9] = (int)i10;  ob[10] = (int)i11;  ob[11] = (int)i12;
    ob[12] = (int)i13;  ob[13] = (int)i14;  ob[14] = (int)i15;  ob[15] = (int)i16;
}

// ---------------- BN finalize ----------------
__global__ void finalize_bn(const float* __restrict__ part, float* __restrict__ bn,
                            const float* g0, const float* b0, const float* g1,
                            const float* b1, const float* g2, const float* b2,
                            const float* scg, const float* scb, int mapA, int mapB) {
    int L = (blockIdx.x == 0) ? mapA : mapB;
    int o = threadIdx.x;
    const float* g = (L == 0) ? g0 : (L == 1) ? g1 : (L == 2) ? g2 : scg;
    const float* b = (L == 0) ? b0 : (L == 1) ? b1 : (L == 2) ? b2 : scb;
    float cnt = (L == 3) ? (float)(NB * NP) : (float)(NB * NP * KNN);
    float s = 0.f, ss = 0.f;
    for (int slot = 0; slot < SLOTS; ++slot) {
        s  += part[((L * SLOTS + slot) * 2 + 0) * 64 + o];
        ss += part[((L * SLOTS + slot) * 2 + 1) * 64 + o];
    }
    float mu  = s / cnt;
    float var = fmaxf(ss / cnt - mu * mu, 0.f);
    float sc  = g[o] * rsqrtf(var + 1e-5f);
    bn[L * 128 + o]      = sc;
    bn[L * 128 + 64 + o] = b[o] - mu * sc;
}

#define MFMA16(a, b, c) __builtin_amdgcn_mfma_f32_16x16x32_bf16(a, b, c, 0, 0, 0)

// ---------------- MFMA MLP phases: single-buffer chained persistence -------
// (R17 structure, proven) now FLAT: GRID_MLP=4096 blocks, one iteration of
// the 2-group-ILP body — 4x the independent waves to hide y-buffer load/store
// latency now that per-group compute is small. All indexing identical
// (gbA = bid, gbB = bid + 4096 covers [0, 8192)).
template <int PHASE>
__global__ __launch_bounds__(256)
void mlp_phase(const u16* __restrict__ fb16, const int* __restrict__ idx,
               const u16* __restrict__ Wn, const u16* __restrict__ Wc,
               const u16* __restrict__ W1b, const u16* __restrict__ W2b,
               const u16* __restrict__ scWb, const float* __restrict__ bn,
               float* __restrict__ part, u16* __restrict__ ybuf,
               float* __restrict__ out) {
    __shared__ char AbA[128 * 128];       // group A: 128 rows x 64ch bf16, swizzled
    __shared__ char AbB[128 * 128];       // group B
    __shared__ char ceA[NPB * 128];       // center rows
    __shared__ char ceB[NPB * 128];
    __shared__ float scsA[NPB][64];       // P4 shortcut values (wave-private rows)
    __shared__ float scsB[NPB][64];

    const int tid = threadIdx.x;
    const int lane = tid & 63;
    const int w = tid >> 6;               // wave 0..3: rows w*32..+31, points 2w,2w+1
    const int l15 = lane & 15;
    const int g4 = lane >> 4;
    const int r0 = w * 32 + l15, r1 = r0 + 16;
    const int sw0 = (r0 & 7) << 4;
    // gather geometry (fixed per thread)
    const int gr_ = w * 32 + (lane >> 1);
    const int gh_ = lane & 1;
    const int gp_ = gr_ >> 4;
    const int gk_ = gr_ & 15;
    const int gsw_ = (gr_ & 7) << 4;
    const int cr_ = 2 * w + ((lane >> 4) & 1);

    const int gbA = blockIdx.x;
    const int gbB = gbA + GRID_MLP;
    const int nA = gbA >> 6, nB = gbB >> 6;
    const size_t rbA = (size_t)nA * NP + (gbA & 63) * NPB;
    const size_t rbB = (size_t)nB * NP + (gbB & 63) * NPB;

    f32x4 accA[2][4], accB[2][4];

    auto layer2 = [&](const u16* Wb) {
#pragma unroll
        for (int ks = 0; ks < 2; ++ks) {
            bf8v aA0 = *(const bf8v*)(AbA + r0 * 128 + ((ks * 64 + g4 * 16) ^ sw0));
            bf8v aA1 = *(const bf8v*)(AbA + r1 * 128 + ((ks * 64 + g4 * 16) ^ sw0));
            bf8v aB0 = *(const bf8v*)(AbB + r0 * 128 + ((ks * 64 + g4 * 16) ^ sw0));
            bf8v aB1 = *(const bf8v*)(AbB + r1 * 128 + ((ks * 64 + g4 * 16) ^ sw0));
#pragma unroll
            for (int ct = 0; ct < 4; ++ct) {
                bf8v b = *(const bf8v*)((const char*)Wb + (ct * 16 + l15) * 128 + ks * 64 + g4 * 16);
                accA[0][ct] = MFMA16(aA0, b, accA[0][ct]);
                accA[1][ct] = MFMA16(aA1, b, accA[1][ct]);
                accB[0][ct] = MFMA16(aB0, b, accB[0][ct]);
                accB[1][ct] = MFMA16(aB1, b, accB[1][ct]);
            }
        }
    };
    auto layerC2 = [&](const u16* Wb) {
#pragma unroll
        for (int ks = 0; ks < 2; ++ks) {
            bf8v cA0 = *(const bf8v*)(ceA + (2 * w) * 128 + ks * 64 + g4 * 16);
            bf8v cA1 = *(const bf8v*)(ceA + (2 * w + 1) * 128 + ks * 64 + g4 * 16);
            bf8v cB0 = *(const bf8v*)(ceB + (2 * w) * 128 + ks * 64 + g4 * 16);
            bf8v cB1 = *(const bf8v*)(ceB + (2 * w + 1) * 128 + ks * 64 + g4 * 16);
#pragma unroll
            for (int ct = 0; ct < 4; ++ct) {
                bf8v b = *(const bf8v*)((const char*)Wb + (ct * 16 + l15) * 128 + ks * 64 + g4 * 16);
                accA[0][ct] = MFMA16(cA0, b, accA[0][ct]);
                accA[1][ct] = MFMA16(cA1, b, accA[1][ct]);
                accB[0][ct] = MFMA16(cB0, b, accB[0][ct]);
                accB[1][ct] = MFMA16(cB1, b, accB[1][ct]);
            }
        }
    };
    auto store_acc = [&]() {          // coalesced 64B/thread bf16 store
        u16* ya = ybuf + ((size_t)gbA * 256 + tid) * 32;
        u16* yc = ybuf + ((size_t)gbB * 256 + tid) * 32;
#pragma unroll
        for (int c4 = 0; c4 < 4; ++c4) {
            US8 ua, ub;
#pragma unroll
            for (int e = 0; e < 8; ++e) {
                int i = c4 * 8 + e;
                ua.v[e] = f2bf(accA[i >> 4][(i >> 2) & 3][i & 3]);
                ub.v[e] = f2bf(accB[i >> 4][(i >> 2) & 3][i & 3]);
            }
            ((US8*)ya)[c4] = ua;
            ((US8*)yc)[c4] = ub;
        }
    };
    auto load_acc = [&]() {
        const u16* ya = ybuf + ((size_t)gbA * 256 + tid) * 32;
        const u16* yc = ybuf + ((size_t)gbB * 256 + tid) * 32;
#pragma unroll
        for (int c4 = 0; c4 < 4; ++c4) {
            US8 ua = ((const US8*)ya)[c4];
            US8 ub = ((const US8*)yc)[c4];
#pragma unroll
            for (int e = 0; e < 8; ++e) {
                int i = c4 * 8 + e;
                accA[i >> 4][(i >> 2) & 3][i & 3] = bf2f(ua.v[e]);
                accB[i >> 4][(i >> 2) & 3][i & 3] = bf2f(ub.v[e]);
            }
        }
    };
    auto load_centers = [&]() {
        if (lane < 32) {
            ((uint2*)(ceA + cr_ * 128))[lane & 15] =
                ((const uint2*)(fb16 + (rbA + cr_) * CH))[lane & 15];
            ((uint2*)(ceB + cr_ * 128))[lane & 15] =
                ((const uint2*)(fb16 + (rbB + cr_) * CH))[lane & 15];
        }
    };
    auto stats2 = [&](int L) {
#pragma unroll
        for (int ct = 0; ct < 4; ++ct) {
            float a = 0.f, b = 0.f, c = 0.f, d = 0.f;
#pragma unroll
            for (int rt = 0; rt < 2; ++rt)
#pragma unroll
                for (int j = 0; j < 4; ++j) {
                    float vA = accA[rt][ct][j]; a += vA; b += vA * vA;
                    float vB = accB[rt][ct][j]; c += vB; d += vB * vB;
                }
            a += __shfl_xor(a, 16); a += __shfl_xor(a, 32);
            b += __shfl_xor(b, 16); b += __shfl_xor(b, 32);
            c += __shfl_xor(c, 16); c += __shfl_xor(c, 32);
            d += __shfl_xor(d, 16); d += __shfl_xor(d, 32);
            if (lane < 16) {
                int sA = (gbA * 4 + w) & (SLOTS - 1);
                int sB = (gbB * 4 + w) & (SLOTS - 1);
                int ch = ct * 16 + lane;
                atomicAdd(&part[((L * SLOTS + sA) * 2 + 0) * 64 + ch], a);
                atomicAdd(&part[((L * SLOTS + sA) * 2 + 1) * 64 + ch], b);
                atomicAdd(&part[((L * SLOTS + sB) * 2 + 0) * 64 + ch], c);
                atomicAdd(&part[((L * SLOTS + sB) * 2 + 1) * 64 + ch], d);
            }
        }
    };
    auto bnwb2 = [&](int L) {
#pragma unroll
        for (int ct = 0; ct < 4; ++ct) {
            int ch = ct * 16 + l15;
            float sc = bn[L * 128 + ch], sh = bn[L * 128 + 64 + ch];
#pragma unroll
            for (int rt = 0; rt < 2; ++rt)
#pragma unroll
                for (int j = 0; j < 4; ++j) {
                    int gr = w * 32 + rt * 16 + g4 * 4 + j;
                    int off = gr * 128 + ((ch * 2) ^ ((gr & 7) << 4));
                    float vA = fmaxf(fmaf(accA[rt][ct][j], sc, sh), 0.f);
                    float vB = fmaxf(fmaf(accB[rt][ct][j], sc, sh), 0.f);
                    *(u16*)(AbA + off) = f2bf(vA);
                    *(u16*)(AbB + off) = f2bf(vB);
                    accA[rt][ct][j] = 0.f;
                    accB[rt][ct][j] = 0.f;
                }
        }
    };

    if (PHASE == 1) {
        // ---- gather + L1 + persist y1 + stats(0) + shortcut stats ----
        int srcA = idx[(rbA + gp_) * KNN + gk_];
        int srcB = idx[(rbB + gp_) * KNN + gk_];
        const US8* gA = (const US8*)(fb16 + ((size_t)nA * NP + srcA) * CH + gh_ * 32);
        const US8* gB = (const US8*)(fb16 + ((size_t)nB * NP + srcB) * CH + gh_ * 32);
        US8 aq0 = gA[0], aq1 = gA[1], aq2 = gA[2], aq3 = gA[3];
        US8 bq0 = gB[0], bq1 = gB[1], bq2 = gB[2], bq3 = gB[3];
        uint2 acen = ((const uint2*)(fb16 + (rbA + cr_) * CH))[lane & 15];
        uint2 bcen = ((const uint2*)(fb16 + (rbB + cr_) * CH))[lane & 15];
        char* ra = AbA + gr_ * 128;
        *(US8*)(ra + ((gh_ * 64 +  0) ^ gsw_)) = aq0;
        *(US8*)(ra + ((gh_ * 64 + 16) ^ gsw_)) = aq1;
        *(US8*)(ra + ((gh_ * 64 + 32) ^ gsw_)) = aq2;
        *(US8*)(ra + ((gh_ * 64 + 48) ^ gsw_)) = aq3;
        char* rb = AbB + gr_ * 128;
        *(US8*)(rb + ((gh_ * 64 +  0) ^ gsw_)) = bq0;
        *(US8*)(rb + ((gh_ * 64 + 16) ^ gsw_)) = bq1;
        *(US8*)(rb + ((gh_ * 64 + 32) ^ gsw_)) = bq2;
        *(US8*)(rb + ((gh_ * 64 + 48) ^ gsw_)) = bq3;
        if (lane < 32) {
            ((uint2*)(ceA + cr_ * 128))[lane & 15] = acen;
            ((uint2*)(ceB + cr_ * 128))[lane & 15] = bcen;
        }
#pragma unroll
        for (int rt = 0; rt < 2; ++rt)
#pragma unroll
            for (int ct = 0; ct < 4; ++ct) {
                accA[rt][ct] = (f32x4){0.f, 0.f, 0.f, 0.f};
                accB[rt][ct] = (f32x4){0.f, 0.f, 0.f, 0.f};
            }
        layer2(Wn);
        layerC2(Wc);
        store_acc();
        stats2(0);
        // shortcut MFMA + masked stats (valid: g4==0, j<2) -> L=3
        f32x4 shA[4], shB[4];
#pragma unroll
        for (int ct = 0; ct < 4; ++ct) {
            shA[ct] = (f32x4){0.f, 0.f, 0.f, 0.f};
            shB[ct] = (f32x4){0.f, 0.f, 0.f, 0.f};
        }
#pragma unroll
        for (int ks = 0; ks < 2; ++ks) {
            int arow = (l15 < 2) ? (2 * w + l15) : (2 * w);
            bf8v aA = *(const bf8v*)(ceA + arow * 128 + ks * 64 + g4 * 16);
            bf8v aB = *(const bf8v*)(ceB + arow * 128 + ks * 64 + g4 * 16);
#pragma unroll
            for (int ct = 0; ct < 4; ++ct) {
                bf8v b = *(const bf8v*)((const char*)scWb + (ct * 16 + l15) * 128 + ks * 64 + g4 * 16);
                shA[ct] = MFMA16(aA, b, shA[ct]);
                shB[ct] = MFMA16(aB, b, shB[ct]);
            }
        }
#pragma unroll
        for (int ct = 0; ct < 4; ++ct) {
            float uA = (g4 == 0) ? shA[ct][0] : 0.f;
            float vA = (g4 == 0) ? shA[ct][1] : 0.f;
            float uB = (g4 == 0) ? shB[ct][0] : 0.f;
            float vB = (g4 == 0) ? shB[ct][1] : 0.f;
            float a = uA + vA, b = uA * uA + vA * vA;
            float c = uB + vB, d = uB * uB + vB * vB;
            a += __shfl_xor(a, 16); a += __shfl_xor(a, 32);
            b += __shfl_xor(b, 16); b += __shfl_xor(b, 32);
            c += __shfl_xor(c, 16); c += __shfl_xor(c, 32);
            d += __shfl_xor(d, 16); d += __shfl_xor(d, 32);
            if (lane < 16) {
                int sA = (gbA * 4 + w) & (SLOTS - 1);
                int sB = (gbB * 4 + w) & (SLOTS - 1);
                int ch = ct * 16 + lane;
                atomicAdd(&part[((3 * SLOTS + sA) * 2 + 0) * 64 + ch], a);
                atomicAdd(&part[((3 * SLOTS + sA) * 2 + 1) * 64 + ch], b);
                atomicAdd(&part[((3 * SLOTS + sB) * 2 + 0) * 64 + ch], c);
                atomicAdd(&part[((3 * SLOTS + sB) * 2 + 1) * 64 + ch], d);
            }
        }
        return;
    }

    if (PHASE == 2) {
        load_acc();                   // y1
        bnwb2(0);
        layer2(W1b);
        store_acc();                  // y2 in place (slot thread-private)
        stats2(1);
        return;
    }
    if (PHASE == 3) {
        load_acc();                   // y2
        bnwb2(1);
        layer2(W2b);
        store_acc();                  // y3 in place
        stats2(2);
        return;
    }

    // ---- PHASE 4: load y3 direct + mean_k + shortcut + out ----
    load_acc();                       // y3
    load_centers();
    {
        float m0A[4], m1A[4], m0B[4], m1B[4];
#pragma unroll
        for (int ct = 0; ct < 4; ++ct) {
            int ch = ct * 16 + l15;
            float sc = bn[2 * 128 + ch], sh = bn[2 * 128 + 64 + ch];
            float ma = 0.f, mb = 0.f, mc = 0.f, md = 0.f;
#pragma unroll
            for (int j = 0; j < 4; ++j) {
                ma += fmaxf(fmaf(accA[0][ct][j], sc, sh), 0.f);
                mb += fmaxf(fmaf(accA[1][ct][j], sc, sh), 0.f);
                mc += fmaxf(fmaf(accB[0][ct][j], sc, sh), 0.f);
                md += fmaxf(fmaf(accB[1][ct][j], sc, sh), 0.f);
            }
            ma += __shfl_xor(ma, 16); ma += __shfl_xor(ma, 32);
            mb += __shfl_xor(mb, 16); mb += __shfl_xor(mb, 32);
            mc += __shfl_xor(mc, 16); mc += __shfl_xor(mc, 32);
            md += __shfl_xor(md, 16); md += __shfl_xor(md, 32);
            m0A[ct] = ma; m1A[ct] = mb; m0B[ct] = mc; m1B[ct] = md;
        }
        f32x4 shA[4], shB[4];
#pragma unroll
        for (int ct = 0; ct < 4; ++ct) {
            shA[ct] = (f32x4){0.f, 0.f, 0.f, 0.f};
            shB[ct] = (f32x4){0.f, 0.f, 0.f, 0.f};
        }
#pragma unroll
        for (int ks = 0; ks < 2; ++ks) {
            int arow = (l15 < 2) ? (2 * w + l15) : (2 * w);
            bf8v aA = *(const bf8v*)(ceA + arow * 128 + ks * 64 + g4 * 16);
            bf8v aB = *(const bf8v*)(ceB + arow * 128 + ks * 64 + g4 * 16);
#pragma unroll
            for (int ct = 0; ct < 4; ++ct) {
                bf8v b = *(const bf8v*)((const char*)scWb + (ct * 16 + l15) * 128 + ks * 64 + g4 * 16);
                shA[ct] = MFMA16(aA, b, shA[ct]);
                shB[ct] = MFMA16(aB, b, shB[ct]);
            }
        }
        if (g4 == 0) {
#pragma unroll
            for (int ct = 0; ct < 4; ++ct) {
                int ch = ct * 16 + l15;
                float s3 = bn[3 * 128 + ch], h3 = bn[3 * 128 + 64 + ch];
                scsA[2 * w + 0][ch] = fmaxf(fmaf(shA[ct][0], s3, h3), 0.f);
                scsA[2 * w + 1][ch] = fmaxf(fmaf(shA[ct][1], s3, h3), 0.f);
                scsB[2 * w + 0][ch] = fmaxf(fmaf(shB[ct][0], s3, h3), 0.f);
                scsB[2 * w + 1][ch] = fmaxf(fmaf(shB[ct][1], s3, h3), 0.f);
            }
        }
        int ph = g4 >> 1;             // 0: p=2w, 1: p=2w+1
        int p = 2 * w + ph;
        int cb2 = g4 & 1;
        int ch0 = (cb2 * 2) * 16 + l15;
        int ch1 = ch0 + 16;
        {
            float lo0 = cb2 ? m0A[2] : m0A[0], hi0 = cb2 ? m1A[2] : m1A[0];
            float lo1 = cb2 ? m0A[3] : m0A[1], hi1 = cb2 ? m1A[3] : m1A[1];
            float mva = ph ? hi0 : lo0;
            float mvb = ph ? hi1 : lo1;
            float* ob = out + (rbA + p) * CH;
            ob[ch0] = mva * 0.0625f + scsA[p][ch0];
            ob[ch1] = mvb * 0.0625f + scsA[p][ch1];
        }
        {
            float lo0 = cb2 ? m0B[2] : m0B[0], hi0 = cb2 ? m1B[2] : m1B[0];
            float lo1 = cb2 ? m0B[3] : m0B[1], hi1 = cb2 ? m1B[3] : m1B[1];
            float mva = ph ? hi0 : lo0;
            float mvb = ph ? hi1 : lo1;
            float* ob = out + (rbB + p) * CH;
            ob[ch0] = mva * 0.0625f + scsB[p][ch0];
            ob[ch1] = mvb * 0.0625f + scsB[p][ch1];
        }
    }
}

extern "C" void kernel_launch(void* const* d_in, const int* in_sizes, int n_in,
                              void* d_out, int out_size, void* d_ws, size_t ws_size,
                              hipStream_t stream) {
    const float* points = (const float*)d_in[0];
    const float* feats  = (const float*)d_in[1];
    const float* W0  = (const float*)d_in[2];
    const float* g0  = (const float*)d_in[3];
    const float* b0  = (const float*)d_in[4];
    const float* W1  = (const float*)d_in[5];
    const float* g1  = (const float*)d_in[6];
    const float* b1  = (const float*)d_in[7];
    const float* W2  = (const float*)d_in[8];
    const float* g2  = (const float*)d_in[9];
    const float* b2  = (const float*)d_in[10];
    const float* scW = (const float*)d_in[11];
    const float* scg = (const float*)d_in[12];
    const float* scb = (const float*)d_in[13];
    float* out = (float*)d_out;

    char* ws = (char*)d_ws;
    int*   idx  = (int*)(ws + OFF_IDX);
    float* part = (float*)(ws + OFF_PART);
    float* bn   = (float*)(ws + OFF_BN);
    u16*   Wn   = (u16*)(ws + OFF_WN);
    u16*   Wc   = (u16*)(ws + OFF_WC);
    u16*   W1b  = (u16*)(ws + OFF_W1B);
    u16*   W2b  = (u16*)(ws + OFF_W2B);
    u16*   scWb = (u16*)(ws + OFF_SCWB);
    u16*   fb16 = (u16*)(ws + OFF_FB16);
    u16*   y1   = (u16*)(ws + OFF_Y1);

    hipMemsetAsync(part, 0, PART_BYTES, stream);
    prep_weights<<<16, 256, 0, stream>>>(W0, W1, W2, scW, Wn, Wc, W1b, W2b, scWb);
    feats_to_bf16<<<2048, 256, 0, stream>>>(feats, fb16);
    knn_kernel<<<NB * 2, 256, 0, stream>>>(points, idx);

    mlp_phase<1><<<GRID_MLP, 256, 0, stream>>>(fb16, idx, Wn, Wc, W1b, W2b, scWb, bn, part, y1, out);
    finalize_bn<<<2, 64, 0, stream>>>(part, bn, g0, b0, g1, b1, g2, b2, scg, scb, 0, 3);
    mlp_phase<2><<<GRID_MLP, 256, 0, stream>>>(fb16, idx, Wn, Wc, W1b, W2b, scWb, bn, part, y1, out);
    finalize_bn<<<1, 64, 0, stream>>>(part, bn, g0, b0, g1, b1, g2, b2, scg, scb, 1, 1);
    mlp_phase<3><<<GRID_MLP, 256, 0, stream>>>(fb16, idx, Wn, Wc, W1b, W2b, scWb, bn, part, y1, out);
    finalize_bn<<<1, 64, 0, stream>>>(part, bn, g0, b0, g1, b1, g2, b2, scg, scb, 2, 2);
    mlp_phase<4><<<GRID_MLP, 256, 0, stream>>>(fb16, idx, Wn, Wc, W1b, W2b, scWb, bn, part, y1, out);
}

// Round 19
// 433.343 us; speedup vs baseline: 1.0797x; 1.0797x over previous
//
#include <hip/hip_runtime.h>
#include <stdint.h>

typedef unsigned short u16;
typedef __attribute__((ext_vector_type(8))) short bf8v;    // 8 bf16 MFMA frag
typedef __attribute__((ext_vector_type(4))) float f32x4;   // C/D frag

#define NB   128
#define NP   512
#define KNN  16
#define CH   64
#define NPB  8                       // points per group
#define GPH  (NB * NP / NPB)         // 8192 groups per phase
#define GRID_MLP 1024                // persistent blocks (R17 proven; 4096 regressed)
#define GPB  8                       // groups per block (2 in flight per iter)
#define SLOTS 512

// ---------------- workspace layout (bytes) ----------------
#define OFF_IDX   0                  // 4 MB
#define OFF_PART  0x400000           // 1 MB: [L][slot][sum/ssq][ch]
#define PART_BYTES (4 * SLOTS * 2 * 64 * 4)
#define OFF_BN    0x500000           // 2 KB
#define OFF_WN    0x500800           // 8 KB bf16 [o][c]
#define OFF_WC    0x502800
#define OFF_W1B   0x504800
#define OFF_W2B   0x506800
#define OFF_SCWB  0x508800
#define OFF_FB16  0x600000           // 8.4 MB bf16 feats [n*NP+p][64]
#define OFF_Y1    0x1000000          // 134 MB bf16 y frags [group][tid][32]
#define Y1_BYTES  ((size_t)GPH * 256 * 32 * 2)
// knn partial lists overlap Y1 (dead until mlp_phase<1>): [pt][half][34] u32
#define OFF_KPART OFF_Y1

__device__ __forceinline__ u16 f2bf(float f) {
    union { float f; unsigned u; } v; v.f = f;
    unsigned r = v.u + 0x7fffu + ((v.u >> 16) & 1u);       // RNE
    return (u16)(r >> 16);
}
__device__ __forceinline__ float bf2f(u16 b) {
    union { unsigned u; float f; } v; v.u = ((unsigned)b) << 16;
    return v.f;
}
struct alignas(16) US8 { u16 v[8]; };
__device__ __forceinline__ US8 pack8(float4 f0, float4 f1) {
    US8 u;
    u.v[0]=f2bf(f0.x); u.v[1]=f2bf(f0.y); u.v[2]=f2bf(f0.z); u.v[3]=f2bf(f0.w);
    u.v[4]=f2bf(f1.x); u.v[5]=f2bf(f1.y); u.v[6]=f2bf(f1.z); u.v[7]=f2bf(f1.w);
    return u;
}

// ---------------- weight prep ----------------
__global__ void prep_weights(const float* __restrict__ W0, const float* __restrict__ W1,
                             const float* __restrict__ W2, const float* __restrict__ scW,
                             u16* Wn, u16* Wc, u16* W1b, u16* W2b, u16* scWb) {
    int i = blockIdx.x * 256 + threadIdx.x;                // i = o*64 + c
    if (i < 4096) {
        int o = i >> 6, c = i & 63;
        float a = W0[o * 128 + c], b = W0[o * 128 + 64 + c];
        Wc[i] = f2bf(a - b);
        Wn[i] = f2bf(b);
        W1b[i]  = f2bf(W1[i]);
        W2b[i]  = f2bf(W2[i]);
        scWb[i] = f2bf(scW[i]);
    }
}

// u32 split-key stable insert (R16, verified): candidates arrive in ascending
// q within each half, so strict-< stable insertion on the transformed distance
// reproduces (d,q) lexicographic order exactly.
#define INS32(ub, qq) do { if ((ub) < d16) {                                  \
    bool c00=(ub)<d00, c01=(ub)<d01, c02=(ub)<d02, c03=(ub)<d03,              \
         c04=(ub)<d04, c05=(ub)<d05, c06=(ub)<d06, c07=(ub)<d07,              \
         c08=(ub)<d08, c09=(ub)<d09, c10=(ub)<d10, c11=(ub)<d11,              \
         c12=(ub)<d12, c13=(ub)<d13, c14=(ub)<d14, c15=(ub)<d15;              \
    d16 = c15 ? d15 : (ub);                 i16 = c15 ? i15 : (qq);           \
    d15 = c14 ? d14 : (c15 ? (ub) : d15);   i15 = c14 ? i14 : (c15 ? (qq) : i15); \
    d14 = c13 ? d13 : (c14 ? (ub) : d14);   i14 = c13 ? i13 : (c14 ? (qq) : i14); \
    d13 = c12 ? d12 : (c13 ? (ub) : d13);   i13 = c12 ? i12 : (c13 ? (qq) : i13); \
    d12 = c11 ? d11 : (c12 ? (ub) : d12);   i12 = c11 ? i11 : (c12 ? (qq) : i12); \
    d11 = c10 ? d10 : (c11 ? (ub) : d11);   i11 = c10 ? i10 : (c11 ? (qq) : i11); \
    d10 = c09 ? d09 : (c10 ? (ub) : d10);   i10 = c09 ? i09 : (c10 ? (qq) : i10); \
    d09 = c08 ? d08 : (c09 ? (ub) : d09);   i09 = c08 ? i08 : (c09 ? (qq) : i09); \
    d08 = c07 ? d07 : (c08 ? (ub) : d08);   i08 = c07 ? i07 : (c08 ? (qq) : i08); \
    d07 = c06 ? d06 : (c07 ? (ub) : d07);   i07 = c06 ? i06 : (c07 ? (qq) : i07); \
    d06 = c05 ? d05 : (c06 ? (ub) : d06);   i06 = c05 ? i05 : (c06 ? (qq) : i06); \
    d05 = c04 ? d04 : (c05 ? (ub) : d05);   i05 = c04 ? i04 : (c05 ? (qq) : i05); \
    d04 = c03 ? d03 : (c04 ? (ub) : d04);   i04 = c03 ? i03 : (c04 ? (qq) : i04); \
    d03 = c02 ? d02 : (c03 ? (ub) : d03);   i03 = c02 ? i02 : (c03 ? (qq) : i03); \
    d02 = c01 ? d01 : (c02 ? (ub) : d02);   i02 = c01 ? i01 : (c02 ? (qq) : i02); \
    d01 = c00 ? d00 : (c01 ? (ub) : d01);   i01 = c00 ? i00 : (c01 ? (qq) : i01); \
    d00 = c00 ? (ub) : d00;                 i00 = c00 ? (qq) : i00;           \
} } while (0)

#define KDECL unsigned d00=~0u,d01=~0u,d02=~0u,d03=~0u,d04=~0u,d05=~0u,       \
    d06=~0u,d07=~0u,d08=~0u,d09=~0u,d10=~0u,d11=~0u,d12=~0u,d13=~0u,          \
    d14=~0u,d15=~0u,d16=~0u;                                                  \
    unsigned i00=0,i01=0,i02=0,i03=0,i04=0,i05=0,i06=0,i07=0,                 \
    i08=0,i09=0,i10=0,i11=0,i12=0,i13=0,i14=0,i15=0,i16=0

// ---------------- KNN scan: candidate-half per BLOCK (R16 chain shape) ----
// 512 blocks: b -> batch n=b>>2, point-half ph=(b>>1)&1, candidate-half
// qh=b&1. Each thread scans 256 candidates with the proven R16 chain (same
// register footprint / issue behavior; R10's in-wave split is NOT repeated).
// Prologue converts feats->bf16 grid-stride (independent work, fills the
// dep-bound scan's idle issue slots; removes a launch). Partial top-17
// (d[17],i[17]) per (point, half) to ws (y1 region, dead until P1).
__global__ __launch_bounds__(256)
void knn_scan(const float* __restrict__ pts, const float* __restrict__ feats,
              u16* __restrict__ fb16, unsigned* __restrict__ kpart) {
#pragma clang fp contract(off)
    __shared__ __align__(16) float4 sp[256];
    const int tid = threadIdx.x;
    {   // feats -> bf16 (grid-stride over 524288 US8 groups)
        const size_t nv = (size_t)NB * NP * CH / 8;
        for (size_t i = (size_t)blockIdx.x * 256 + tid; i < nv; i += (size_t)gridDim.x * 256) {
            float4 f0 = ((const float4*)feats)[i * 2];
            float4 f1 = ((const float4*)feats)[i * 2 + 1];
            ((US8*)fb16)[i] = pack8(f0, f1);
        }
    }
    const int b = blockIdx.x;
    const int n = b >> 2;
    const int ph = (b >> 1) & 1;
    const int qh = b & 1;
    const float* pb = pts + (size_t)n * NP * 2;
    {   // stage this block's candidate half
        int i = qh * 256 + tid;
        float x = pb[i * 2], y = pb[i * 2 + 1];
        float r = x * x + y * y;                  // matches np: mul, mul, add
        sp[tid] = make_float4(x, y, r, 0.f);
    }
    __syncthreads();
    const int p = ph * 256 + tid;
    float xp = pb[p * 2], yp = pb[p * 2 + 1];
    float rp = xp * xp + yp * yp;                 // same op order as staging

    KDECL;
    const int q0 = qh << 8;
    for (int t = 0; t < 256; ++t) {
        float4 sq = sp[t];
        float m = xp * sq.x + yp * sq.y;          // einsum inner order
        float d = (rp - 2.0f * m) + sq.z;         // (r - 2m) + r^T order
        unsigned int ub = __float_as_uint(d);
        ub = (ub & 0x80000000u) ? ~ub : (ub | 0x80000000u);
        INS32(ub, (unsigned)(q0 + t));
    }
    unsigned* pp = kpart + (((size_t)(n * NP + p)) * 2 + qh) * 34;
    pp[ 0]=d00; pp[ 1]=d01; pp[ 2]=d02; pp[ 3]=d03; pp[ 4]=d04; pp[ 5]=d05;
    pp[ 6]=d06; pp[ 7]=d07; pp[ 8]=d08; pp[ 9]=d09; pp[10]=d10; pp[11]=d11;
    pp[12]=d12; pp[13]=d13; pp[14]=d14; pp[15]=d15; pp[16]=d16;
    pp[17]=i00; pp[18]=i01; pp[19]=i02; pp[20]=i03; pp[21]=i04; pp[22]=i05;
    pp[23]=i06; pp[24]=i07; pp[25]=i08; pp[26]=i09; pp[27]=i10; pp[28]=i11;
    pp[29]=i12; pp[30]=i13; pp[31]=i14; pp[32]=i15; pp[33]=i16;
}

// ---------------- KNN merge: combine the two sorted 17-lists -------------
// List0 (q<256) into regs; list1 entries (higher q) inserted in order via
// the same stable strict-< chain -> exact (d,q) lexicographic order.
__global__ __launch_bounds__(256)
void knn_merge(const unsigned* __restrict__ kpart, int* __restrict__ idx) {
    const size_t pt = (size_t)blockIdx.x * 256 + threadIdx.x;
    const unsigned* p0 = kpart + (pt * 2 + 0) * 34;
    const unsigned* p1 = kpart + (pt * 2 + 1) * 34;
    unsigned d00=p0[0], d01=p0[1], d02=p0[2], d03=p0[3], d04=p0[4],
             d05=p0[5], d06=p0[6], d07=p0[7], d08=p0[8], d09=p0[9],
             d10=p0[10],d11=p0[11],d12=p0[12],d13=p0[13],d14=p0[14],
             d15=p0[15],d16=p0[16];
    unsigned i00=p0[17],i01=p0[18],i02=p0[19],i03=p0[20],i04=p0[21],
             i05=p0[22],i06=p0[23],i07=p0[24],i08=p0[25],i09=p0[26],
             i10=p0[27],i11=p0[28],i12=p0[29],i13=p0[30],i14=p0[31],
             i15=p0[32],i16=p0[33];
#pragma unroll
    for (int j = 0; j < 17; ++j) {
        unsigned ub = p1[j], qq = p1[17 + j];
        INS32(ub, qq);
    }
    int* ob = idx + pt * KNN;                     // drop slot 0 (self)
    ob[ 0] = (int)i01;  ob[ 1] = (int)i02;  ob[ 2] = (int)i03;  ob[ 3] = (int)i04;
    ob[ 4] = (int)i05;  ob[ 5] = (int)i06;  ob[ 6] = (int)i07;  ob[ 7] = (int)i08;
    ob[ 8] = (int)i09;  ob[ 9] = (int)i10;  ob[10] = (int)i11;  ob[11] = (int)i12;
    ob[12] = (int)i13;  ob[13] = (int)i14;  ob[14] = (int)i15;  ob[15] = (int)i16;
}

// ---------------- BN finalize ----------------
__global__ void finalize_bn(const float* __restrict__ part, float* __restrict__ bn,
                            const float* g0, const float* b0, const float* g1,
                            const float* b1, const float* g2, const float* b2,
                            const float* scg, const float* scb, int mapA, int mapB) {
    int L = (blockIdx.x == 0) ? mapA : mapB;
    int o = threadIdx.x;
    const float* g = (L == 0) ? g0 : (L == 1) ? g1 : (L == 2) ? g2 : scg;
    const float* b = (L == 0) ? b0 : (L == 1) ? b1 : (L == 2) ? b2 : scb;
    float cnt = (L == 3) ? (float)(NB * NP) : (float)(NB * NP * KNN);
    float s = 0.f, ss = 0.f;
    for (int slot = 0; slot < SLOTS; ++slot) {
        s  += part[((L * SLOTS + slot) * 2 + 0) * 64 + o];
        ss += part[((L * SLOTS + slot) * 2 + 1) * 64 + o];
    }
    float mu  = s / cnt;
    float var = fmaxf(ss / cnt - mu * mu, 0.f);
    float sc  = g[o] * rsqrtf(var + 1e-5f);
    bn[L * 128 + o]      = sc;
    bn[L * 128 + 64 + o] = b[o] - mu * sc;
}

#define MFMA16(a, b, c) __builtin_amdgcn_mfma_f32_16x16x32_bf16(a, b, c, 0, 0, 0)

// ---------------- MFMA MLP phases (R17 proven form, unchanged) -------------
template <int PHASE>
__global__ __launch_bounds__(256)
void mlp_phase(const u16* __restrict__ fb16, const int* __restrict__ idx,
               const u16* __restrict__ Wn, const u16* __restrict__ Wc,
               const u16* __restrict__ W1b, const u16* __restrict__ W2b,
               const u16* __restrict__ scWb, const float* __restrict__ bn,
               float* __restrict__ part, u16* __restrict__ ybuf,
               float* __restrict__ out) {
    __shared__ char AbA[128 * 128];
    __shared__ char AbB[128 * 128];
    __shared__ char ceA[NPB * 128];
    __shared__ char ceB[NPB * 128];
    __shared__ float scsA[NPB][64];
    __shared__ float scsB[NPB][64];

    const int tid = threadIdx.x;
    const int lane = tid & 63;
    const int w = tid >> 6;
    const int l15 = lane & 15;
    const int g4 = lane >> 4;
    const int r0 = w * 32 + l15, r1 = r0 + 16;
    const int sw0 = (r0 & 7) << 4;
    const int gr_ = w * 32 + (lane >> 1);
    const int gh_ = lane & 1;
    const int gp_ = gr_ >> 4;
    const int gk_ = gr_ & 15;
    const int gsw_ = (gr_ & 7) << 4;
    const int cr_ = 2 * w + ((lane >> 4) & 1);

    for (int it = 0; it < GPB / 2; ++it) {
        const int gbA = blockIdx.x + it * (2 * GRID_MLP);
        const int gbB = gbA + GRID_MLP;
        const int nA = gbA >> 6, nB = gbB >> 6;
        const size_t rbA = (size_t)nA * NP + (gbA & 63) * NPB;
        const size_t rbB = (size_t)nB * NP + (gbB & 63) * NPB;

        f32x4 accA[2][4], accB[2][4];

        auto layer2 = [&](const u16* Wb) {
#pragma unroll
            for (int ks = 0; ks < 2; ++ks) {
                bf8v aA0 = *(const bf8v*)(AbA + r0 * 128 + ((ks * 64 + g4 * 16) ^ sw0));
                bf8v aA1 = *(const bf8v*)(AbA + r1 * 128 + ((ks * 64 + g4 * 16) ^ sw0));
                bf8v aB0 = *(const bf8v*)(AbB + r0 * 128 + ((ks * 64 + g4 * 16) ^ sw0));
                bf8v aB1 = *(const bf8v*)(AbB + r1 * 128 + ((ks * 64 + g4 * 16) ^ sw0));
#pragma unroll
                for (int ct = 0; ct < 4; ++ct) {
                    bf8v b = *(const bf8v*)((const char*)Wb + (ct * 16 + l15) * 128 + ks * 64 + g4 * 16);
                    accA[0][ct] = MFMA16(aA0, b, accA[0][ct]);
                    accA[1][ct] = MFMA16(aA1, b, accA[1][ct]);
                    accB[0][ct] = MFMA16(aB0, b, accB[0][ct]);
                    accB[1][ct] = MFMA16(aB1, b, accB[1][ct]);
                }
            }
        };
        auto layerC2 = [&](const u16* Wb) {
#pragma unroll
            for (int ks = 0; ks < 2; ++ks) {
                bf8v cA0 = *(const bf8v*)(ceA + (2 * w) * 128 + ks * 64 + g4 * 16);
                bf8v cA1 = *(const bf8v*)(ceA + (2 * w + 1) * 128 + ks * 64 + g4 * 16);
                bf8v cB0 = *(const bf8v*)(ceB + (2 * w) * 128 + ks * 64 + g4 * 16);
                bf8v cB1 = *(const bf8v*)(ceB + (2 * w + 1) * 128 + ks * 64 + g4 * 16);
#pragma unroll
                for (int ct = 0; ct < 4; ++ct) {
                    bf8v b = *(const bf8v*)((const char*)Wb + (ct * 16 + l15) * 128 + ks * 64 + g4 * 16);
                    accA[0][ct] = MFMA16(cA0, b, accA[0][ct]);
                    accA[1][ct] = MFMA16(cA1, b, accA[1][ct]);
                    accB[0][ct] = MFMA16(cB0, b, accB[0][ct]);
                    accB[1][ct] = MFMA16(cB1, b, accB[1][ct]);
                }
            }
        };
        auto store_acc = [&]() {
            u16* ya = ybuf + ((size_t)gbA * 256 + tid) * 32;
            u16* yc = ybuf + ((size_t)gbB * 256 + tid) * 32;
#pragma unroll
            for (int c4 = 0; c4 < 4; ++c4) {
                US8 ua, ub;
#pragma unroll
                for (int e = 0; e < 8; ++e) {
                    int i = c4 * 8 + e;
                    ua.v[e] = f2bf(accA[i >> 4][(i >> 2) & 3][i & 3]);
                    ub.v[e] = f2bf(accB[i >> 4][(i >> 2) & 3][i & 3]);
                }
                ((US8*)ya)[c4] = ua;
                ((US8*)yc)[c4] = ub;
            }
        };
        auto load_acc = [&]() {
            const u16* ya = ybuf + ((size_t)gbA * 256 + tid) * 32;
            const u16* yc = ybuf + ((size_t)gbB * 256 + tid) * 32;
#pragma unroll
            for (int c4 = 0; c4 < 4; ++c4) {
                US8 ua = ((const US8*)ya)[c4];
                US8 ub = ((const US8*)yc)[c4];
#pragma unroll
                for (int e = 0; e < 8; ++e) {
                    int i = c4 * 8 + e;
                    accA[i >> 4][(i >> 2) & 3][i & 3] = bf2f(ua.v[e]);
                    accB[i >> 4][(i >> 2) & 3][i & 3] = bf2f(ub.v[e]);
                }
            }
        };
        auto load_centers = [&]() {
            if (lane < 32) {
                ((uint2*)(ceA + cr_ * 128))[lane & 15] =
                    ((const uint2*)(fb16 + (rbA + cr_) * CH))[lane & 15];
                ((uint2*)(ceB + cr_ * 128))[lane & 15] =
                    ((const uint2*)(fb16 + (rbB + cr_) * CH))[lane & 15];
            }
        };
        auto stats2 = [&](int L) {
#pragma unroll
            for (int ct = 0; ct < 4; ++ct) {
                float a = 0.f, b = 0.f, c = 0.f, d = 0.f;
#pragma unroll
                for (int rt = 0; rt < 2; ++rt)
#pragma unroll
                    for (int j = 0; j < 4; ++j) {
                        float vA = accA[rt][ct][j]; a += vA; b += vA * vA;
                        float vB = accB[rt][ct][j]; c += vB; d += vB * vB;
                    }
                a += __shfl_xor(a, 16); a += __shfl_xor(a, 32);
                b += __shfl_xor(b, 16); b += __shfl_xor(b, 32);
                c += __shfl_xor(c, 16); c += __shfl_xor(c, 32);
                d += __shfl_xor(d, 16); d += __shfl_xor(d, 32);
                if (lane < 16) {
                    int sA = (gbA * 4 + w) & (SLOTS - 1);
                    int sB = (gbB * 4 + w) & (SLOTS - 1);
                    int ch = ct * 16 + lane;
                    atomicAdd(&part[((L * SLOTS + sA) * 2 + 0) * 64 + ch], a);
                    atomicAdd(&part[((L * SLOTS + sA) * 2 + 1) * 64 + ch], b);
                    atomicAdd(&part[((L * SLOTS + sB) * 2 + 0) * 64 + ch], c);
                    atomicAdd(&part[((L * SLOTS + sB) * 2 + 1) * 64 + ch], d);
                }
            }
        };
        auto bnwb2 = [&](int L) {
#pragma unroll
            for (int ct = 0; ct < 4; ++ct) {
                int ch = ct * 16 + l15;
                float sc = bn[L * 128 + ch], sh = bn[L * 128 + 64 + ch];
#pragma unroll
                for (int rt = 0; rt < 2; ++rt)
#pragma unroll
                    for (int j = 0; j < 4; ++j) {
                        int gr = w * 32 + rt * 16 + g4 * 4 + j;
                        int off = gr * 128 + ((ch * 2) ^ ((gr & 7) << 4));
                        float vA = fmaxf(fmaf(accA[rt][ct][j], sc, sh), 0.f);
                        float vB = fmaxf(fmaf(accB[rt][ct][j], sc, sh), 0.f);
                        *(u16*)(AbA + off) = f2bf(vA);
                        *(u16*)(AbB + off) = f2bf(vB);
                        accA[rt][ct][j] = 0.f;
                        accB[rt][ct][j] = 0.f;
                    }
            }
        };

        if (PHASE == 1) {
            int srcA = idx[(rbA + gp_) * KNN + gk_];
            int srcB = idx[(rbB + gp_) * KNN + gk_];
            const US8* gA = (const US8*)(fb16 + ((size_t)nA * NP + srcA) * CH + gh_ * 32);
            const US8* gB = (const US8*)(fb16 + ((size_t)nB * NP + srcB) * CH + gh_ * 32);
            US8 aq0 = gA[0], aq1 = gA[1], aq2 = gA[2], aq3 = gA[3];
            US8 bq0 = gB[0], bq1 = gB[1], bq2 = gB[2], bq3 = gB[3];
            uint2 acen = ((const uint2*)(fb16 + (rbA + cr_) * CH))[lane & 15];
            uint2 bcen = ((const uint2*)(fb16 + (rbB + cr_) * CH))[lane & 15];
            char* ra = AbA + gr_ * 128;
            *(US8*)(ra + ((gh_ * 64 +  0) ^ gsw_)) = aq0;
            *(US8*)(ra + ((gh_ * 64 + 16) ^ gsw_)) = aq1;
            *(US8*)(ra + ((gh_ * 64 + 32) ^ gsw_)) = aq2;
            *(US8*)(ra + ((gh_ * 64 + 48) ^ gsw_)) = aq3;
            char* rb = AbB + gr_ * 128;
            *(US8*)(rb + ((gh_ * 64 +  0) ^ gsw_)) = bq0;
            *(US8*)(rb + ((gh_ * 64 + 16) ^ gsw_)) = bq1;
            *(US8*)(rb + ((gh_ * 64 + 32) ^ gsw_)) = bq2;
            *(US8*)(rb + ((gh_ * 64 + 48) ^ gsw_)) = bq3;
            if (lane < 32) {
                ((uint2*)(ceA + cr_ * 128))[lane & 15] = acen;
                ((uint2*)(ceB + cr_ * 128))[lane & 15] = bcen;
            }
#pragma unroll
            for (int rt = 0; rt < 2; ++rt)
#pragma unroll
                for (int ct = 0; ct < 4; ++ct) {
                    accA[rt][ct] = (f32x4){0.f, 0.f, 0.f, 0.f};
                    accB[rt][ct] = (f32x4){0.f, 0.f, 0.f, 0.f};
                }
            layer2(Wn);
            layerC2(Wc);
            store_acc();
            stats2(0);
            f32x4 shA[4], shB[4];
#pragma unroll
            for (int ct = 0; ct < 4; ++ct) {
                shA[ct] = (f32x4){0.f, 0.f, 0.f, 0.f};
                shB[ct] = (f32x4){0.f, 0.f, 0.f, 0.f};
            }
#pragma unroll
            for (int ks = 0; ks < 2; ++ks) {
                int arow = (l15 < 2) ? (2 * w + l15) : (2 * w);
                bf8v aA = *(const bf8v*)(ceA + arow * 128 + ks * 64 + g4 * 16);
                bf8v aB = *(const bf8v*)(ceB + arow * 128 + ks * 64 + g4 * 16);
#pragma unroll
                for (int ct = 0; ct < 4; ++ct) {
                    bf8v b = *(const bf8v*)((const char*)scWb + (ct * 16 + l15) * 128 + ks * 64 + g4 * 16);
                    shA[ct] = MFMA16(aA, b, shA[ct]);
                    shB[ct] = MFMA16(aB, b, shB[ct]);
                }
            }
#pragma unroll
            for (int ct = 0; ct < 4; ++ct) {
                float uA = (g4 == 0) ? shA[ct][0] : 0.f;
                float vA = (g4 == 0) ? shA[ct][1] : 0.f;
                float uB = (g4 == 0) ? shB[ct][0] : 0.f;
                float vB = (g4 == 0) ? shB[ct][1] : 0.f;
                float a = uA + vA, b = uA * uA + vA * vA;
                float c = uB + vB, d = uB * uB + vB * vB;
                a += __shfl_xor(a, 16); a += __shfl_xor(a, 32);
                b += __shfl_xor(b, 16); b += __shfl_xor(b, 32);
                c += __shfl_xor(c, 16); c += __shfl_xor(c, 32);
                d += __shfl_xor(d, 16); d += __shfl_xor(d, 32);
                if (lane < 16) {
                    int sA = (gbA * 4 + w) & (SLOTS - 1);
                    int sB = (gbB * 4 + w) & (SLOTS - 1);
                    int ch = ct * 16 + lane;
                    atomicAdd(&part[((3 * SLOTS + sA) * 2 + 0) * 64 + ch], a);
                    atomicAdd(&part[((3 * SLOTS + sA) * 2 + 1) * 64 + ch], b);
                    atomicAdd(&part[((3 * SLOTS + sB) * 2 + 0) * 64 + ch], c);
                    atomicAdd(&part[((3 * SLOTS + sB) * 2 + 1) * 64 + ch], d);
                }
            }
            continue;
        }

        if (PHASE == 2) {
            load_acc();
            bnwb2(0);
            layer2(W1b);
            store_acc();
            stats2(1);
            continue;
        }
        if (PHASE == 3) {
            load_acc();
            bnwb2(1);
            layer2(W2b);
            store_acc();
            stats2(2);
            continue;
        }

        load_acc();
        load_centers();
        {
            float m0A[4], m1A[4], m0B[4], m1B[4];
#pragma unroll
            for (int ct = 0; ct < 4; ++ct) {
                int ch = ct * 16 + l15;
                float sc = bn[2 * 128 + ch], sh = bn[2 * 128 + 64 + ch];
                float ma = 0.f, mb = 0.f, mc = 0.f, md = 0.f;
#pragma unroll
                for (int j = 0; j < 4; ++j) {
                    ma += fmaxf(fmaf(accA[0][ct][j], sc, sh), 0.f);
                    mb += fmaxf(fmaf(accA[1][ct][j], sc, sh), 0.f);
                    mc += fmaxf(fmaf(accB[0][ct][j], sc, sh), 0.f);
                    md += fmaxf(fmaf(accB[1][ct][j], sc, sh), 0.f);
                }
                ma += __shfl_xor(ma, 16); ma += __shfl_xor(ma, 32);
                mb += __shfl_xor(mb, 16); mb += __shfl_xor(mb, 32);
                mc += __shfl_xor(mc, 16); mc += __shfl_xor(mc, 32);
                md += __shfl_xor(md, 16); md += __shfl_xor(md, 32);
                m0A[ct] = ma; m1A[ct] = mb; m0B[ct] = mc; m1B[ct] = md;
            }
            f32x4 shA[4], shB[4];
#pragma unroll
            for (int ct = 0; ct < 4; ++ct) {
                shA[ct] = (f32x4){0.f, 0.f, 0.f, 0.f};
                shB[ct] = (f32x4){0.f, 0.f, 0.f, 0.f};
            }
#pragma unroll
            for (int ks = 0; ks < 2; ++ks) {
                int arow = (l15 < 2) ? (2 * w + l15) : (2 * w);
                bf8v aA = *(const bf8v*)(ceA + arow * 128 + ks * 64 + g4 * 16);
                bf8v aB = *(const bf8v*)(ceB + arow * 128 + ks * 64 + g4 * 16);
#pragma unroll
                for (int ct = 0; ct < 4; ++ct) {
                    bf8v b = *(const bf8v*)((const char*)scWb + (ct * 16 + l15) * 128 + ks * 64 + g4 * 16);
                    shA[ct] = MFMA16(aA, b, shA[ct]);
                    shB[ct] = MFMA16(aB, b, shB[ct]);
                }
            }
            if (g4 == 0) {
#pragma unroll
                for (int ct = 0; ct < 4; ++ct) {
                    int ch = ct * 16 + l15;
                    float s3 = bn[3 * 128 + ch], h3 = bn[3 * 128 + 64 + ch];
                    scsA[2 * w + 0][ch] = fmaxf(fmaf(shA[ct][0], s3, h3), 0.f);
                    scsA[2 * w + 1][ch] = fmaxf(fmaf(shA[ct][1], s3, h3), 0.f);
                    scsB[2 * w + 0][ch] = fmaxf(fmaf(shB[ct][0], s3, h3), 0.f);
                    scsB[2 * w + 1][ch] = fmaxf(fmaf(shB[ct][1], s3, h3), 0.f);
                }
            }
            int ph = g4 >> 1;
            int p = 2 * w + ph;
            int cb2 = g4 & 1;
            int ch0 = (cb2 * 2) * 16 + l15;
            int ch1 = ch0 + 16;
            {
                float lo0 = cb2 ? m0A[2] : m0A[0], hi0 = cb2 ? m1A[2] : m1A[0];
                float lo1 = cb2 ? m0A[3] : m0A[1], hi1 = cb2 ? m1A[3] : m1A[1];
                float mva = ph ? hi0 : lo0;
                float mvb = ph ? hi1 : lo1;
                float* ob = out + (rbA + p) * CH;
                ob[ch0] = mva * 0.0625f + scsA[p][ch0];
                ob[ch1] = mvb * 0.0625f + scsA[p][ch1];
            }
            {
                float lo0 = cb2 ? m0B[2] : m0B[0], hi0 = cb2 ? m1B[2] : m1B[0];
                float lo1 = cb2 ? m0B[3] : m0B[1], hi1 = cb2 ? m1B[3] : m1B[1];
                float mva = ph ? hi0 : lo0;
                float mvb = ph ? hi1 : lo1;
                float* ob = out + (rbB + p) * CH;
                ob[ch0] = mva * 0.0625f + scsB[p][ch0];
                ob[ch1] = mvb * 0.0625f + scsB[p][ch1];
            }
        }
    }
}

extern "C" void kernel_launch(void* const* d_in, const int* in_sizes, int n_in,
                              void* d_out, int out_size, void* d_ws, size_t ws_size,
                              hipStream_t stream) {
    const float* points = (const float*)d_in[0];
    const float* feats  = (const float*)d_in[1];
    const float* W0  = (const float*)d_in[2];
    const float* g0  = (const float*)d_in[3];
    const float* b0  = (const float*)d_in[4];
    const float* W1  = (const float*)d_in[5];
    const float* g1  = (const float*)d_in[6];
    const float* b1  = (const float*)d_in[7];
    const float* W2  = (const float*)d_in[8];
    const float* g2  = (const float*)d_in[9];
    const float* b2  = (const float*)d_in[10];
    const float* scW = (const float*)d_in[11];
    const float* scg = (const float*)d_in[12];
    const float* scb = (const float*)d_in[13];
    float* out = (float*)d_out;

    char* ws = (char*)d_ws;
    int*   idx  = (int*)(ws + OFF_IDX);
    float* part = (float*)(ws + OFF_PART);
    float* bn   = (float*)(ws + OFF_BN);
    u16*   Wn   = (u16*)(ws + OFF_WN);
    u16*   Wc   = (u16*)(ws + OFF_WC);
    u16*   W1b  = (u16*)(ws + OFF_W1B);
    u16*   W2b  = (u16*)(ws + OFF_W2B);
    u16*   scWb = (u16*)(ws + OFF_SCWB);
    u16*   fb16 = (u16*)(ws + OFF_FB16);
    u16*   y1   = (u16*)(ws + OFF_Y1);
    unsigned* kp = (unsigned*)(ws + OFF_KPART);   // overlaps y1 (dead until P1)

    hipMemsetAsync(part, 0, PART_BYTES, stream);
    prep_weights<<<16, 256, 0, stream>>>(W0, W1, W2, scW, Wn, Wc, W1b, W2b, scWb);
    knn_scan<<<NB * 4, 256, 0, stream>>>(points, feats, fb16, kp);
    knn_merge<<<NB * 2, 256, 0, stream>>>(kp, idx);

    mlp_phase<1><<<GRID_MLP, 256, 0, stream>>>(fb16, idx, Wn, Wc, W1b, W2b, scWb, bn, part, y1, out);
    finalize_bn<<<2, 64, 0, stream>>>(part, bn, g0, b0, g1, b1, g2, b2, scg, scb, 0, 3);
    mlp_phase<2><<<GRID_MLP, 256, 0, stream>>>(fb16, idx, Wn, Wc, W1b, W2b, scWb, bn, part, y1, out);
    finalize_bn<<<1, 64, 0, stream>>>(part, bn, g0, b0, g1, b1, g2, b2, scg, scb, 1, 1);
    mlp_phase<3><<<GRID_MLP, 256, 0, stream>>>(fb16, idx, Wn, Wc, W1b, W2b, scWb, bn, part, y1, out);
    finalize_bn<<<1, 64, 0, stream>>>(part, bn, g0, b0, g1, b1, g2, b2, scg, scb, 2, 2);
    mlp_phase<4><<<GRID_MLP, 256, 0, stream>>>(fb16, idx, Wn, Wc, W1b, W2b, scWb, bn, part, y1, out);
}

// Round 20
// 429.865 us; speedup vs baseline: 1.0884x; 1.0081x over previous
//
#include <hip/hip_runtime.h>
#include <stdint.h>

typedef unsigned short u16;
typedef __attribute__((ext_vector_type(8))) short bf8v;    // 8 bf16 MFMA frag
typedef __attribute__((ext_vector_type(4))) float f32x4;   // C/D frag

#define NB   128
#define NP   512
#define KNN  16
#define CH   64
#define NPB  8                       // points per group
#define GPH  (NB * NP / NPB)         // 8192 groups per phase
#define GRID_MLP 1024                // persistent blocks (R17 proven; 4096 regressed)
#define GPB  8                       // groups per block (2 in flight per iter)
#define SLOTS 512

// ---------------- workspace layout (bytes) ----------------
#define OFF_IDX   0                  // 4 MB
#define OFF_PART  0x400000           // 1 MB: [L][slot][sum/ssq][ch]
#define PART_BYTES (4 * SLOTS * 2 * 64 * 4)
#define OFF_BN    0x500000           // 2 KB
#define OFF_WN    0x500800           // 8 KB bf16 [o][c]
#define OFF_WC    0x502800
#define OFF_W1B   0x504800
#define OFF_W2B   0x506800
#define OFF_SCWB  0x508800
#define OFF_FB16  0x600000           // 8.4 MB bf16 feats [n*NP+p][64]
#define OFF_Y1    0x1000000          // 134 MB bf16 y frags [group][tid][32]
#define Y1_BYTES  ((size_t)GPH * 256 * 32 * 2)
// knn partial lists overlap Y1 (dead until mlp_phase<1>): [pt][quarter][34] u32
#define OFF_KPART OFF_Y1

__device__ __forceinline__ u16 f2bf(float f) {
    union { float f; unsigned u; } v; v.f = f;
    unsigned r = v.u + 0x7fffu + ((v.u >> 16) & 1u);       // RNE
    return (u16)(r >> 16);
}
__device__ __forceinline__ float bf2f(u16 b) {
    union { unsigned u; float f; } v; v.u = ((unsigned)b) << 16;
    return v.f;
}
struct alignas(16) US8 { u16 v[8]; };
__device__ __forceinline__ US8 pack8(float4 f0, float4 f1) {
    US8 u;
    u.v[0]=f2bf(f0.x); u.v[1]=f2bf(f0.y); u.v[2]=f2bf(f0.z); u.v[3]=f2bf(f0.w);
    u.v[4]=f2bf(f1.x); u.v[5]=f2bf(f1.y); u.v[6]=f2bf(f1.z); u.v[7]=f2bf(f1.w);
    return u;
}

// ---------------- weight prep ----------------
__global__ void prep_weights(const float* __restrict__ W0, const float* __restrict__ W1,
                             const float* __restrict__ W2, const float* __restrict__ scW,
                             u16* Wn, u16* Wc, u16* W1b, u16* W2b, u16* scWb) {
    int i = blockIdx.x * 256 + threadIdx.x;                // i = o*64 + c
    if (i < 4096) {
        int o = i >> 6, c = i & 63;
        float a = W0[o * 128 + c], b = W0[o * 128 + 64 + c];
        Wc[i] = f2bf(a - b);
        Wn[i] = f2bf(b);
        W1b[i]  = f2bf(W1[i]);
        W2b[i]  = f2bf(W2[i]);
        scWb[i] = f2bf(scW[i]);
    }
}

// u32 split-key stable insert (R16, verified): candidates arrive in ascending
// q within each quarter, so strict-< stable insertion on the transformed
// distance reproduces (d,q) lexicographic order exactly.
#define INS32(ub, qq) do { if ((ub) < d16) {                                  \
    bool c00=(ub)<d00, c01=(ub)<d01, c02=(ub)<d02, c03=(ub)<d03,              \
         c04=(ub)<d04, c05=(ub)<d05, c06=(ub)<d06, c07=(ub)<d07,              \
         c08=(ub)<d08, c09=(ub)<d09, c10=(ub)<d10, c11=(ub)<d11,              \
         c12=(ub)<d12, c13=(ub)<d13, c14=(ub)<d14, c15=(ub)<d15;              \
    d16 = c15 ? d15 : (ub);                 i16 = c15 ? i15 : (qq);           \
    d15 = c14 ? d14 : (c15 ? (ub) : d15);   i15 = c14 ? i14 : (c15 ? (qq) : i15); \
    d14 = c13 ? d13 : (c14 ? (ub) : d14);   i14 = c13 ? i13 : (c14 ? (qq) : i14); \
    d13 = c12 ? d12 : (c13 ? (ub) : d13);   i13 = c12 ? i12 : (c13 ? (qq) : i13); \
    d12 = c11 ? d11 : (c12 ? (ub) : d12);   i12 = c11 ? i11 : (c12 ? (qq) : i12); \
    d11 = c10 ? d10 : (c11 ? (ub) : d11);   i11 = c10 ? i10 : (c11 ? (qq) : i11); \
    d10 = c09 ? d09 : (c10 ? (ub) : d10);   i10 = c09 ? i09 : (c10 ? (qq) : i10); \
    d09 = c08 ? d08 : (c09 ? (ub) : d09);   i09 = c08 ? i08 : (c09 ? (qq) : i09); \
    d08 = c07 ? d07 : (c08 ? (ub) : d08);   i08 = c07 ? i07 : (c08 ? (qq) : i08); \
    d07 = c06 ? d06 : (c07 ? (ub) : d07);   i07 = c06 ? i06 : (c07 ? (qq) : i07); \
    d06 = c05 ? d05 : (c06 ? (ub) : d06);   i06 = c05 ? i05 : (c06 ? (qq) : i06); \
    d05 = c04 ? d04 : (c05 ? (ub) : d05);   i05 = c04 ? i04 : (c05 ? (qq) : i05); \
    d04 = c03 ? d03 : (c04 ? (ub) : d04);   i04 = c03 ? i03 : (c04 ? (qq) : i04); \
    d03 = c02 ? d02 : (c03 ? (ub) : d03);   i03 = c02 ? i02 : (c03 ? (qq) : i03); \
    d02 = c01 ? d01 : (c02 ? (ub) : d02);   i02 = c01 ? i01 : (c02 ? (qq) : i02); \
    d01 = c00 ? d00 : (c01 ? (ub) : d01);   i01 = c00 ? i00 : (c01 ? (qq) : i01); \
    d00 = c00 ? (ub) : d00;                 i00 = c00 ? (qq) : i00;           \
} } while (0)

#define KDECL unsigned d00=~0u,d01=~0u,d02=~0u,d03=~0u,d04=~0u,d05=~0u,       \
    d06=~0u,d07=~0u,d08=~0u,d09=~0u,d10=~0u,d11=~0u,d12=~0u,d13=~0u,          \
    d14=~0u,d15=~0u,d16=~0u;                                                  \
    unsigned i00=0,i01=0,i02=0,i03=0,i04=0,i05=0,i06=0,i07=0,                 \
    i08=0,i09=0,i10=0,i11=0,i12=0,i13=0,i14=0,i15=0,i16=0

// ---------------- KNN scan: candidate-QUARTER per block (R19 mechanism) ---
// 1024 blocks: n=b>>3, point-half ph=(b>>2)&1, candidate-quarter qq=b&3.
// Each thread scans 128 candidates with the proven R16 chain shape (R19
// showed the block-level split keeps issue efficiency; VALUBusy 56->70%).
// Prologue folds feats->bf16 (independent grid-stride work).
__global__ __launch_bounds__(256)
void knn_scan(const float* __restrict__ pts, const float* __restrict__ feats,
              u16* __restrict__ fb16, unsigned* __restrict__ kpart) {
#pragma clang fp contract(off)
    __shared__ __align__(16) float4 sp[128];
    const int tid = threadIdx.x;
    {   // feats -> bf16 (grid-stride over 524288 US8 groups)
        const size_t nv = (size_t)NB * NP * CH / 8;
        for (size_t i = (size_t)blockIdx.x * 256 + tid; i < nv; i += (size_t)gridDim.x * 256) {
            float4 f0 = ((const float4*)feats)[i * 2];
            float4 f1 = ((const float4*)feats)[i * 2 + 1];
            ((US8*)fb16)[i] = pack8(f0, f1);
        }
    }
    const int b = blockIdx.x;
    const int n = b >> 3;
    const int ph = (b >> 2) & 1;
    const int qq = b & 3;
    const float* pb = pts + (size_t)n * NP * 2;
    if (tid < 128) {                              // stage this block's quarter
        int i = qq * 128 + tid;
        float x = pb[i * 2], y = pb[i * 2 + 1];
        float r = x * x + y * y;                  // matches np: mul, mul, add
        sp[tid] = make_float4(x, y, r, 0.f);
    }
    __syncthreads();
    const int p = ph * 256 + tid;
    float xp = pb[p * 2], yp = pb[p * 2 + 1];
    float rp = xp * xp + yp * yp;                 // same op order as staging

    KDECL;
    const int q0 = qq << 7;
    for (int t = 0; t < 128; ++t) {
        float4 sq = sp[t];
        float m = xp * sq.x + yp * sq.y;          // einsum inner order
        float d = (rp - 2.0f * m) + sq.z;         // (r - 2m) + r^T order
        unsigned int ub = __float_as_uint(d);
        ub = (ub & 0x80000000u) ? ~ub : (ub | 0x80000000u);
        INS32(ub, (unsigned)(q0 + t));
    }
    unsigned* pp = kpart + (((size_t)(n * NP + p)) * 4 + qq) * 34;
    pp[ 0]=d00; pp[ 1]=d01; pp[ 2]=d02; pp[ 3]=d03; pp[ 4]=d04; pp[ 5]=d05;
    pp[ 6]=d06; pp[ 7]=d07; pp[ 8]=d08; pp[ 9]=d09; pp[10]=d10; pp[11]=d11;
    pp[12]=d12; pp[13]=d13; pp[14]=d14; pp[15]=d15; pp[16]=d16;
    pp[17]=i00; pp[18]=i01; pp[19]=i02; pp[20]=i03; pp[21]=i04; pp[22]=i05;
    pp[23]=i06; pp[24]=i07; pp[25]=i08; pp[26]=i09; pp[27]=i10; pp[28]=i11;
    pp[29]=i12; pp[30]=i13; pp[31]=i14; pp[32]=i15; pp[33]=i16;
}

// ---------------- KNN merge: combine 4 sorted 17-lists -------------------
// Quarter 0 into regs; quarters 1..3 (ascending q ranges) inserted in order
// via the same stable strict-< chain -> exact (d,q) lexicographic order.
__global__ __launch_bounds__(256)
void knn_merge(const unsigned* __restrict__ kpart, int* __restrict__ idx) {
    const size_t pt = (size_t)blockIdx.x * 256 + threadIdx.x;
    const unsigned* p0 = kpart + (pt * 4 + 0) * 34;
    unsigned d00=p0[0], d01=p0[1], d02=p0[2], d03=p0[3], d04=p0[4],
             d05=p0[5], d06=p0[6], d07=p0[7], d08=p0[8], d09=p0[9],
             d10=p0[10],d11=p0[11],d12=p0[12],d13=p0[13],d14=p0[14],
             d15=p0[15],d16=p0[16];
    unsigned i00=p0[17],i01=p0[18],i02=p0[19],i03=p0[20],i04=p0[21],
             i05=p0[22],i06=p0[23],i07=p0[24],i08=p0[25],i09=p0[26],
             i10=p0[27],i11=p0[28],i12=p0[29],i13=p0[30],i14=p0[31],
             i15=p0[32],i16=p0[33];
#pragma unroll
    for (int h = 1; h < 4; ++h) {
        const unsigned* p1 = kpart + (pt * 4 + h) * 34;
#pragma unroll
        for (int j = 0; j < 17; ++j) {
            unsigned ub = p1[j], qq = p1[17 + j];
            INS32(ub, qq);
        }
    }
    int* ob = idx + pt * KNN;                     // drop slot 0 (self)
    ob[ 0] = (int)i01;  ob[ 1] = (int)i02;  ob[ 2] = (int)i03;  ob[ 3] = (int)i04;
    ob[ 4] = (int)i05;  ob[ 5] = (int)i06;  ob[ 6] = (int)i07;  ob[ 7] = (int)i08;
    ob[ 8] = (int)i09;  ob[ 9] = (int)i10;  ob[10] = (int)i11;  ob[11] = (int)i12;
    ob[12] = (int)i13;  ob[13] = (int)i14;  ob[14] = (int)i15;  ob[15] = (int)i16;
}

// ---------------- BN finalize ----------------
__global__ void finalize_bn(const float* __restrict__ part, float* __restrict__ bn,
                            const float* g0, const float* b0, const float* g1,
                            const float* b1, const float* g2, const float* b2,
                            const float* scg, const float* scb, int mapA, int mapB) {
    int L = (blockIdx.x == 0) ? mapA : mapB;
    int o = threadIdx.x;
    const float* g = (L == 0) ? g0 : (L == 1) ? g1 : (L == 2) ? g2 : scg;
    const float* b = (L == 0) ? b0 : (L == 1) ? b1 : (L == 2) ? b2 : scb;
    float cnt = (L == 3) ? (float)(NB * NP) : (float)(NB * NP * KNN);
    float s = 0.f, ss = 0.f;
    for (int slot = 0; slot < SLOTS; ++slot) {
        s  += part[((L * SLOTS + slot) * 2 + 0) * 64 + o];
        ss += part[((L * SLOTS + slot) * 2 + 1) * 64 + o];
    }
    float mu  = s / cnt;
    float var = fmaxf(ss / cnt - mu * mu, 0.f);
    float sc  = g[o] * rsqrtf(var + 1e-5f);
    bn[L * 128 + o]      = sc;
    bn[L * 128 + 64 + o] = b[o] - mu * sc;
}

#define MFMA16(a, b, c) __builtin_amdgcn_mfma_f32_16x16x32_bf16(a, b, c, 0, 0, 0)

// ---------------- MFMA MLP phases (R17 proven form, unchanged) -------------
template <int PHASE>
__global__ __launch_bounds__(256)
void mlp_phase(const u16* __restrict__ fb16, const int* __restrict__ idx,
               const u16* __restrict__ Wn, const u16* __restrict__ Wc,
               const u16* __restrict__ W1b, const u16* __restrict__ W2b,
               const u16* __restrict__ scWb, const float* __restrict__ bn,
               float* __restrict__ part, u16* __restrict__ ybuf,
               float* __restrict__ out) {
    __shared__ char AbA[128 * 128];
    __shared__ char AbB[128 * 128];
    __shared__ char ceA[NPB * 128];
    __shared__ char ceB[NPB * 128];
    __shared__ float scsA[NPB][64];
    __shared__ float scsB[NPB][64];

    const int tid = threadIdx.x;
    const int lane = tid & 63;
    const int w = tid >> 6;
    const int l15 = lane & 15;
    const int g4 = lane >> 4;
    const int r0 = w * 32 + l15, r1 = r0 + 16;
    const int sw0 = (r0 & 7) << 4;
    const int gr_ = w * 32 + (lane >> 1);
    const int gh_ = lane & 1;
    const int gp_ = gr_ >> 4;
    const int gk_ = gr_ & 15;
    const int gsw_ = (gr_ & 7) << 4;
    const int cr_ = 2 * w + ((lane >> 4) & 1);

    for (int it = 0; it < GPB / 2; ++it) {
        const int gbA = blockIdx.x + it * (2 * GRID_MLP);
        const int gbB = gbA + GRID_MLP;
        const int nA = gbA >> 6, nB = gbB >> 6;
        const size_t rbA = (size_t)nA * NP + (gbA & 63) * NPB;
        const size_t rbB = (size_t)nB * NP + (gbB & 63) * NPB;

        f32x4 accA[2][4], accB[2][4];

        auto layer2 = [&](const u16* Wb) {
#pragma unroll
            for (int ks = 0; ks < 2; ++ks) {
                bf8v aA0 = *(const bf8v*)(AbA + r0 * 128 + ((ks * 64 + g4 * 16) ^ sw0));
                bf8v aA1 = *(const bf8v*)(AbA + r1 * 128 + ((ks * 64 + g4 * 16) ^ sw0));
                bf8v aB0 = *(const bf8v*)(AbB + r0 * 128 + ((ks * 64 + g4 * 16) ^ sw0));
                bf8v aB1 = *(const bf8v*)(AbB + r1 * 128 + ((ks * 64 + g4 * 16) ^ sw0));
#pragma unroll
                for (int ct = 0; ct < 4; ++ct) {
                    bf8v b = *(const bf8v*)((const char*)Wb + (ct * 16 + l15) * 128 + ks * 64 + g4 * 16);
                    accA[0][ct] = MFMA16(aA0, b, accA[0][ct]);
                    accA[1][ct] = MFMA16(aA1, b, accA[1][ct]);
                    accB[0][ct] = MFMA16(aB0, b, accB[0][ct]);
                    accB[1][ct] = MFMA16(aB1, b, accB[1][ct]);
                }
            }
        };
        auto layerC2 = [&](const u16* Wb) {
#pragma unroll
            for (int ks = 0; ks < 2; ++ks) {
                bf8v cA0 = *(const bf8v*)(ceA + (2 * w) * 128 + ks * 64 + g4 * 16);
                bf8v cA1 = *(const bf8v*)(ceA + (2 * w + 1) * 128 + ks * 64 + g4 * 16);
                bf8v cB0 = *(const bf8v*)(ceB + (2 * w) * 128 + ks * 64 + g4 * 16);
                bf8v cB1 = *(const bf8v*)(ceB + (2 * w + 1) * 128 + ks * 64 + g4 * 16);
#pragma unroll
                for (int ct = 0; ct < 4; ++ct) {
                    bf8v b = *(const bf8v*)((const char*)Wb + (ct * 16 + l15) * 128 + ks * 64 + g4 * 16);
                    accA[0][ct] = MFMA16(cA0, b, accA[0][ct]);
                    accA[1][ct] = MFMA16(cA1, b, accA[1][ct]);
                    accB[0][ct] = MFMA16(cB0, b, accB[0][ct]);
                    accB[1][ct] = MFMA16(cB1, b, accB[1][ct]);
                }
            }
        };
        auto store_acc = [&]() {
            u16* ya = ybuf + ((size_t)gbA * 256 + tid) * 32;
            u16* yc = ybuf + ((size_t)gbB * 256 + tid) * 32;
#pragma unroll
            for (int c4 = 0; c4 < 4; ++c4) {
                US8 ua, ub;
#pragma unroll
                for (int e = 0; e < 8; ++e) {
                    int i = c4 * 8 + e;
                    ua.v[e] = f2bf(accA[i >> 4][(i >> 2) & 3][i & 3]);
                    ub.v[e] = f2bf(accB[i >> 4][(i >> 2) & 3][i & 3]);
                }
                ((US8*)ya)[c4] = ua;
                ((US8*)yc)[c4] = ub;
            }
        };
        auto load_acc = [&]() {
            const u16* ya = ybuf + ((size_t)gbA * 256 + tid) * 32;
            const u16* yc = ybuf + ((size_t)gbB * 256 + tid) * 32;
#pragma unroll
            for (int c4 = 0; c4 < 4; ++c4) {
                US8 ua = ((const US8*)ya)[c4];
                US8 ub = ((const US8*)yc)[c4];
#pragma unroll
                for (int e = 0; e < 8; ++e) {
                    int i = c4 * 8 + e;
                    accA[i >> 4][(i >> 2) & 3][i & 3] = bf2f(ua.v[e]);
                    accB[i >> 4][(i >> 2) & 3][i & 3] = bf2f(ub.v[e]);
                }
            }
        };
        auto load_centers = [&]() {
            if (lane < 32) {
                ((uint2*)(ceA + cr_ * 128))[lane & 15] =
                    ((const uint2*)(fb16 + (rbA + cr_) * CH))[lane & 15];
                ((uint2*)(ceB + cr_ * 128))[lane & 15] =
                    ((const uint2*)(fb16 + (rbB + cr_) * CH))[lane & 15];
            }
        };
        auto stats2 = [&](int L) {
#pragma unroll
            for (int ct = 0; ct < 4; ++ct) {
                float a = 0.f, b = 0.f, c = 0.f, d = 0.f;
#pragma unroll
                for (int rt = 0; rt < 2; ++rt)
#pragma unroll
                    for (int j = 0; j < 4; ++j) {
                        float vA = accA[rt][ct][j]; a += vA; b += vA * vA;
                        float vB = accB[rt][ct][j]; c += vB; d += vB * vB;
                    }
                a += __shfl_xor(a, 16); a += __shfl_xor(a, 32);
                b += __shfl_xor(b, 16); b += __shfl_xor(b, 32);
                c += __shfl_xor(c, 16); c += __shfl_xor(c, 32);
                d += __shfl_xor(d, 16); d += __shfl_xor(d, 32);
                if (lane < 16) {
                    int sA = (gbA * 4 + w) & (SLOTS - 1);
                    int sB = (gbB * 4 + w) & (SLOTS - 1);
                    int ch = ct * 16 + lane;
                    atomicAdd(&part[((L * SLOTS + sA) * 2 + 0) * 64 + ch], a);
                    atomicAdd(&part[((L * SLOTS + sA) * 2 + 1) * 64 + ch], b);
                    atomicAdd(&part[((L * SLOTS + sB) * 2 + 0) * 64 + ch], c);
                    atomicAdd(&part[((L * SLOTS + sB) * 2 + 1) * 64 + ch], d);
                }
            }
        };
        auto bnwb2 = [&](int L) {
#pragma unroll
            for (int ct = 0; ct < 4; ++ct) {
                int ch = ct * 16 + l15;
                float sc = bn[L * 128 + ch], sh = bn[L * 128 + 64 + ch];
#pragma unroll
                for (int rt = 0; rt < 2; ++rt)
#pragma unroll
                    for (int j = 0; j < 4; ++j) {
                        int gr = w * 32 + rt * 16 + g4 * 4 + j;
                        int off = gr * 128 + ((ch * 2) ^ ((gr & 7) << 4));
                        float vA = fmaxf(fmaf(accA[rt][ct][j], sc, sh), 0.f);
                        float vB = fmaxf(fmaf(accB[rt][ct][j], sc, sh), 0.f);
                        *(u16*)(AbA + off) = f2bf(vA);
                        *(u16*)(AbB + off) = f2bf(vB);
                        accA[rt][ct][j] = 0.f;
                        accB[rt][ct][j] = 0.f;
                    }
            }
        };

        if (PHASE == 1) {
            int srcA = idx[(rbA + gp_) * KNN + gk_];
            int srcB = idx[(rbB + gp_) * KNN + gk_];
            const US8* gA = (const US8*)(fb16 + ((size_t)nA * NP + srcA) * CH + gh_ * 32);
            const US8* gB = (const US8*)(fb16 + ((size_t)nB * NP + srcB) * CH + gh_ * 32);
            US8 aq0 = gA[0], aq1 = gA[1], aq2 = gA[2], aq3 = gA[3];
            US8 bq0 = gB[0], bq1 = gB[1], bq2 = gB[2], bq3 = gB[3];
            uint2 acen = ((const uint2*)(fb16 + (rbA + cr_) * CH))[lane & 15];
            uint2 bcen = ((const uint2*)(fb16 + (rbB + cr_) * CH))[lane & 15];
            char* ra = AbA + gr_ * 128;
            *(US8*)(ra + ((gh_ * 64 +  0) ^ gsw_)) = aq0;
            *(US8*)(ra + ((gh_ * 64 + 16) ^ gsw_)) = aq1;
            *(US8*)(ra + ((gh_ * 64 + 32) ^ gsw_)) = aq2;
            *(US8*)(ra + ((gh_ * 64 + 48) ^ gsw_)) = aq3;
            char* rb = AbB + gr_ * 128;
            *(US8*)(rb + ((gh_ * 64 +  0) ^ gsw_)) = bq0;
            *(US8*)(rb + ((gh_ * 64 + 16) ^ gsw_)) = bq1;
            *(US8*)(rb + ((gh_ * 64 + 32) ^ gsw_)) = bq2;
            *(US8*)(rb + ((gh_ * 64 + 48) ^ gsw_)) = bq3;
            if (lane < 32) {
                ((uint2*)(ceA + cr_ * 128))[lane & 15] = acen;
                ((uint2*)(ceB + cr_ * 128))[lane & 15] = bcen;
            }
#pragma unroll
            for (int rt = 0; rt < 2; ++rt)
#pragma unroll
                for (int ct = 0; ct < 4; ++ct) {
                    accA[rt][ct] = (f32x4){0.f, 0.f, 0.f, 0.f};
                    accB[rt][ct] = (f32x4){0.f, 0.f, 0.f, 0.f};
                }
            layer2(Wn);
            layerC2(Wc);
            store_acc();
            stats2(0);
            f32x4 shA[4], shB[4];
#pragma unroll
            for (int ct = 0; ct < 4; ++ct) {
                shA[ct] = (f32x4){0.f, 0.f, 0.f, 0.f};
                shB[ct] = (f32x4){0.f, 0.f, 0.f, 0.f};
            }
#pragma unroll
            for (int ks = 0; ks < 2; ++ks) {
                int arow = (l15 < 2) ? (2 * w + l15) : (2 * w);
                bf8v aA = *(const bf8v*)(ceA + arow * 128 + ks * 64 + g4 * 16);
                bf8v aB = *(const bf8v*)(ceB + arow * 128 + ks * 64 + g4 * 16);
#pragma unroll
                for (int ct = 0; ct < 4; ++ct) {
                    bf8v b = *(const bf8v*)((const char*)scWb + (ct * 16 + l15) * 128 + ks * 64 + g4 * 16);
                    shA[ct] = MFMA16(aA, b, shA[ct]);
                    shB[ct] = MFMA16(aB, b, shB[ct]);
                }
            }
#pragma unroll
            for (int ct = 0; ct < 4; ++ct) {
                float uA = (g4 == 0) ? shA[ct][0] : 0.f;
                float vA = (g4 == 0) ? shA[ct][1] : 0.f;
                float uB = (g4 == 0) ? shB[ct][0] : 0.f;
                float vB = (g4 == 0) ? shB[ct][1] : 0.f;
                float a = uA + vA, b = uA * uA + vA * vA;
                float c = uB + vB, d = uB * uB + vB * vB;
                a += __shfl_xor(a, 16); a += __shfl_xor(a, 32);
                b += __shfl_xor(b, 16); b += __shfl_xor(b, 32);
                c += __shfl_xor(c, 16); c += __shfl_xor(c, 32);
                d += __shfl_xor(d, 16); d += __shfl_xor(d, 32);
                if (lane < 16) {
                    int sA = (gbA * 4 + w) & (SLOTS - 1);
                    int sB = (gbB * 4 + w) & (SLOTS - 1);
                    int ch = ct * 16 + lane;
                    atomicAdd(&part[((3 * SLOTS + sA) * 2 + 0) * 64 + ch], a);
                    atomicAdd(&part[((3 * SLOTS + sA) * 2 + 1) * 64 + ch], b);
                    atomicAdd(&part[((3 * SLOTS + sB) * 2 + 0) * 64 + ch], c);
                    atomicAdd(&part[((3 * SLOTS + sB) * 2 + 1) * 64 + ch], d);
                }
            }
            continue;
        }

        if (PHASE == 2) {
            load_acc();
            bnwb2(0);
            layer2(W1b);
            store_acc();
            stats2(1);
            continue;
        }
        if (PHASE == 3) {
            load_acc();
            bnwb2(1);
            layer2(W2b);
            store_acc();
            stats2(2);
            continue;
        }

        load_acc();
        load_centers();
        {
            float m0A[4], m1A[4], m0B[4], m1B[4];
#pragma unroll
            for (int ct = 0; ct < 4; ++ct) {
                int ch = ct * 16 + l15;
                float sc = bn[2 * 128 + ch], sh = bn[2 * 128 + 64 + ch];
                float ma = 0.f, mb = 0.f, mc = 0.f, md = 0.f;
#pragma unroll
                for (int j = 0; j < 4; ++j) {
                    ma += fmaxf(fmaf(accA[0][ct][j], sc, sh), 0.f);
                    mb += fmaxf(fmaf(accA[1][ct][j], sc, sh), 0.f);
                    mc += fmaxf(fmaf(accB[0][ct][j], sc, sh), 0.f);
                    md += fmaxf(fmaf(accB[1][ct][j], sc, sh), 0.f);
                }
                ma += __shfl_xor(ma, 16); ma += __shfl_xor(ma, 32);
                mb += __shfl_xor(mb, 16); mb += __shfl_xor(mb, 32);
                mc += __shfl_xor(mc, 16); mc += __shfl_xor(mc, 32);
                md += __shfl_xor(md, 16); md += __shfl_xor(md, 32);
                m0A[ct] = ma; m1A[ct] = mb; m0B[ct] = mc; m1B[ct] = md;
            }
            f32x4 shA[4], shB[4];
#pragma unroll
            for (int ct = 0; ct < 4; ++ct) {
                shA[ct] = (f32x4){0.f, 0.f, 0.f, 0.f};
                shB[ct] = (f32x4){0.f, 0.f, 0.f, 0.f};
            }
#pragma unroll
            for (int ks = 0; ks < 2; ++ks) {
                int arow = (l15 < 2) ? (2 * w + l15) : (2 * w);
                bf8v aA = *(const bf8v*)(ceA + arow * 128 + ks * 64 + g4 * 16);
                bf8v aB = *(const bf8v*)(ceB + arow * 128 + ks * 64 + g4 * 16);
#pragma unroll
                for (int ct = 0; ct < 4; ++ct) {
                    bf8v b = *(const bf8v*)((const char*)scWb + (ct * 16 + l15) * 128 + ks * 64 + g4 * 16);
                    shA[ct] = MFMA16(aA, b, shA[ct]);
                    shB[ct] = MFMA16(aB, b, shB[ct]);
                }
            }
            if (g4 == 0) {
#pragma unroll
                for (int ct = 0; ct < 4; ++ct) {
                    int ch = ct * 16 + l15;
                    float s3 = bn[3 * 128 + ch], h3 = bn[3 * 128 + 64 + ch];
                    scsA[2 * w + 0][ch] = fmaxf(fmaf(shA[ct][0], s3, h3), 0.f);
                    scsA[2 * w + 1][ch] = fmaxf(fmaf(shA[ct][1], s3, h3), 0.f);
                    scsB[2 * w + 0][ch] = fmaxf(fmaf(shB[ct][0], s3, h3), 0.f);
                    scsB[2 * w + 1][ch] = fmaxf(fmaf(shB[ct][1], s3, h3), 0.f);
                }
            }
            int ph = g4 >> 1;
            int p = 2 * w + ph;
            int cb2 = g4 & 1;
            int ch0 = (cb2 * 2) * 16 + l15;
            int ch1 = ch0 + 16;
            {
                float lo0 = cb2 ? m0A[2] : m0A[0], hi0 = cb2 ? m1A[2] : m1A[0];
                float lo1 = cb2 ? m0A[3] : m0A[1], hi1 = cb2 ? m1A[3] : m1A[1];
                float mva = ph ? hi0 : lo0;
                float mvb = ph ? hi1 : lo1;
                float* ob = out + (rbA + p) * CH;
                ob[ch0] = mva * 0.0625f + scsA[p][ch0];
                ob[ch1] = mvb * 0.0625f + scsA[p][ch1];
            }
            {
                float lo0 = cb2 ? m0B[2] : m0B[0], hi0 = cb2 ? m1B[2] : m1B[0];
                float lo1 = cb2 ? m0B[3] : m0B[1], hi1 = cb2 ? m1B[3] : m1B[1];
                float mva = ph ? hi0 : lo0;
                float mvb = ph ? hi1 : lo1;
                float* ob = out + (rbB + p) * CH;
                ob[ch0] = mva * 0.0625f + scsB[p][ch0];
                ob[ch1] = mvb * 0.0625f + scsB[p][ch1];
            }
        }
    }
}

extern "C" void kernel_launch(void* const* d_in, const int* in_sizes, int n_in,
                              void* d_out, int out_size, void* d_ws, size_t ws_size,
                              hipStream_t stream) {
    const float* points = (const float*)d_in[0];
    const float* feats  = (const float*)d_in[1];
    const float* W0  = (const float*)d_in[2];
    const float* g0  = (const float*)d_in[3];
    const float* b0  = (const float*)d_in[4];
    const float* W1  = (const float*)d_in[5];
    const float* g1  = (const float*)d_in[6];
    const float* b1  = (const float*)d_in[7];
    const float* W2  = (const float*)d_in[8];
    const float* g2  = (const float*)d_in[9];
    const float* b2  = (const float*)d_in[10];
    const float* scW = (const float*)d_in[11];
    const float* scg = (const float*)d_in[12];
    const float* scb = (const float*)d_in[13];
    float* out = (float*)d_out;

    char* ws = (char*)d_ws;
    int*   idx  = (int*)(ws + OFF_IDX);
    float* part = (float*)(ws + OFF_PART);
    float* bn   = (float*)(ws + OFF_BN);
    u16*   Wn   = (u16*)(ws + OFF_WN);
    u16*   Wc   = (u16*)(ws + OFF_WC);
    u16*   W1b  = (u16*)(ws + OFF_W1B);
    u16*   W2b  = (u16*)(ws + OFF_W2B);
    u16*   scWb = (u16*)(ws + OFF_SCWB);
    u16*   fb16 = (u16*)(ws + OFF_FB16);
    u16*   y1   = (u16*)(ws + OFF_Y1);
    unsigned* kp = (unsigned*)(ws + OFF_KPART);   // overlaps y1 (dead until P1)

    hipMemsetAsync(part, 0, PART_BYTES, stream);
    prep_weights<<<16, 256, 0, stream>>>(W0, W1, W2, scW, Wn, Wc, W1b, W2b, scWb);
    knn_scan<<<NB * 8, 256, 0, stream>>>(points, feats, fb16, kp);
    knn_merge<<<NB * 2, 256, 0, stream>>>(kp, idx);

    mlp_phase<1><<<GRID_MLP, 256, 0, stream>>>(fb16, idx, Wn, Wc, W1b, W2b, scWb, bn, part, y1, out);
    finalize_bn<<<2, 64, 0, stream>>>(part, bn, g0, b0, g1, b1, g2, b2, scg, scb, 0, 3);
    mlp_phase<2><<<GRID_MLP, 256, 0, stream>>>(fb16, idx, Wn, Wc, W1b, W2b, scWb, bn, part, y1, out);
    finalize_bn<<<1, 64, 0, stream>>>(part, bn, g0, b0, g1, b1, g2, b2, scg, scb, 1, 1);
    mlp_phase<3><<<GRID_MLP, 256, 0, stream>>>(fb16, idx, Wn, Wc, W1b, W2b, scWb, bn, part, y1, out);
    finalize_bn<<<1, 64, 0, stream>>>(part, bn, g0, b0, g1, b1, g2, b2, scg, scb, 2, 2);
    mlp_phase<4><<<GRID_MLP, 256, 0, stream>>>(fb16, idx, Wn, Wc, W1b, W2b, scWb, bn, part, y1, out);
}

// Round 21
// 403.105 us; speedup vs baseline: 1.1607x; 1.0664x over previous
//
#include <hip/hip_runtime.h>
#include <stdint.h>

typedef unsigned short u16;
typedef __attribute__((ext_vector_type(8))) short bf8v;    // 8 bf16 MFMA frag
typedef __attribute__((ext_vector_type(4))) float f32x4;   // C/D frag

#define NB   128
#define NP   512
#define KNN  16
#define CH   64
#define NPB  8                       // points per group
#define GPH  (NB * NP / NPB)         // 8192 groups per phase
#define GRID_MLP 1024                // persistent blocks (R17 proven)
#define GPB  8                       // groups per block (2 in flight per iter)
#define SLOTS 512

// ---------------- workspace layout (bytes) ----------------
#define OFF_IDX   0                  // 4 MB
#define OFF_PART  0x400000           // 1 MB: [L][slot][sum/ssq][ch]
#define PART_BYTES (4 * SLOTS * 2 * 64 * 4)
#define OFF_BN    0x500000           // 2 KB
#define OFF_WN    0x500800           // 8 KB bf16 [o][c]
#define OFF_WC    0x502800
#define OFF_W1B   0x504800
#define OFF_W2B   0x506800
#define OFF_SCWB  0x508800
#define OFF_FB16  0x600000           // 8.4 MB bf16 feats [n*NP+p][64]
#define OFF_Y1    0x1000000          // 134 MB bf16 y frags [group][tid][32]
#define Y1_BYTES  ((size_t)GPH * 256 * 32 * 2)
// knn partial lists overlap Y1 (dead until mlp_phase<1>): [pt][quarter][34] u32
#define OFF_KPART OFF_Y1

__device__ __forceinline__ u16 f2bf(float f) {
    union { float f; unsigned u; } v; v.f = f;
    unsigned r = v.u + 0x7fffu + ((v.u >> 16) & 1u);       // RNE
    return (u16)(r >> 16);
}
__device__ __forceinline__ float bf2f(u16 b) {
    union { unsigned u; float f; } v; v.u = ((unsigned)b) << 16;
    return v.f;
}
struct alignas(16) US8 { u16 v[8]; };
__device__ __forceinline__ US8 pack8(float4 f0, float4 f1) {
    US8 u;
    u.v[0]=f2bf(f0.x); u.v[1]=f2bf(f0.y); u.v[2]=f2bf(f0.z); u.v[3]=f2bf(f0.w);
    u.v[4]=f2bf(f1.x); u.v[5]=f2bf(f1.y); u.v[6]=f2bf(f1.z); u.v[7]=f2bf(f1.w);
    return u;
}

// ---------------- weight prep ----------------
__global__ void prep_weights(const float* __restrict__ W0, const float* __restrict__ W1,
                             const float* __restrict__ W2, const float* __restrict__ scW,
                             u16* Wn, u16* Wc, u16* W1b, u16* W2b, u16* scWb) {
    int i = blockIdx.x * 256 + threadIdx.x;                // i = o*64 + c
    if (i < 4096) {
        int o = i >> 6, c = i & 63;
        float a = W0[o * 128 + c], b = W0[o * 128 + 64 + c];
        Wc[i] = f2bf(a - b);
        Wn[i] = f2bf(b);
        W1b[i]  = f2bf(W1[i]);
        W2b[i]  = f2bf(W2[i]);
        scWb[i] = f2bf(scW[i]);
    }
}

// u32 split-key stable insert (R16, verified): candidates arrive in ascending
// q within each quarter, so strict-< stable insertion on the transformed
// distance reproduces (d,q) lexicographic order exactly.
#define INS32(ub, qq) do { if ((ub) < d16) {                                  \
    bool c00=(ub)<d00, c01=(ub)<d01, c02=(ub)<d02, c03=(ub)<d03,              \
         c04=(ub)<d04, c05=(ub)<d05, c06=(ub)<d06, c07=(ub)<d07,              \
         c08=(ub)<d08, c09=(ub)<d09, c10=(ub)<d10, c11=(ub)<d11,              \
         c12=(ub)<d12, c13=(ub)<d13, c14=(ub)<d14, c15=(ub)<d15;              \
    d16 = c15 ? d15 : (ub);                 i16 = c15 ? i15 : (qq);           \
    d15 = c14 ? d14 : (c15 ? (ub) : d15);   i15 = c14 ? i14 : (c15 ? (qq) : i15); \
    d14 = c13 ? d13 : (c14 ? (ub) : d14);   i14 = c13 ? i13 : (c14 ? (qq) : i14); \
    d13 = c12 ? d12 : (c13 ? (ub) : d13);   i13 = c12 ? i12 : (c13 ? (qq) : i13); \
    d12 = c11 ? d11 : (c12 ? (ub) : d12);   i12 = c11 ? i11 : (c12 ? (qq) : i12); \
    d11 = c10 ? d10 : (c11 ? (ub) : d11);   i11 = c10 ? i10 : (c11 ? (qq) : i11); \
    d10 = c09 ? d09 : (c10 ? (ub) : d10);   i10 = c09 ? i09 : (c10 ? (qq) : i10); \
    d09 = c08 ? d08 : (c09 ? (ub) : d09);   i09 = c08 ? i08 : (c09 ? (qq) : i09); \
    d08 = c07 ? d07 : (c08 ? (ub) : d08);   i08 = c07 ? i07 : (c08 ? (qq) : i08); \
    d07 = c06 ? d06 : (c07 ? (ub) : d07);   i07 = c06 ? i06 : (c07 ? (qq) : i07); \
    d06 = c05 ? d05 : (c06 ? (ub) : d06);   i06 = c05 ? i05 : (c06 ? (qq) : i06); \
    d05 = c04 ? d04 : (c05 ? (ub) : d05);   i05 = c04 ? i04 : (c05 ? (qq) : i05); \
    d04 = c03 ? d03 : (c04 ? (ub) : d04);   i04 = c03 ? i03 : (c04 ? (qq) : i04); \
    d03 = c02 ? d02 : (c03 ? (ub) : d03);   i03 = c02 ? i02 : (c03 ? (qq) : i03); \
    d02 = c01 ? d01 : (c02 ? (ub) : d02);   i02 = c01 ? i01 : (c02 ? (qq) : i02); \
    d01 = c00 ? d00 : (c01 ? (ub) : d01);   i01 = c00 ? i00 : (c01 ? (qq) : i01); \
    d00 = c00 ? (ub) : d00;                 i00 = c00 ? (qq) : i00;           \
} } while (0)

#define KDECL unsigned d00=~0u,d01=~0u,d02=~0u,d03=~0u,d04=~0u,d05=~0u,       \
    d06=~0u,d07=~0u,d08=~0u,d09=~0u,d10=~0u,d11=~0u,d12=~0u,d13=~0u,          \
    d14=~0u,d15=~0u,d16=~0u;                                                  \
    unsigned i00=0,i01=0,i02=0,i03=0,i04=0,i05=0,i06=0,i07=0,                 \
    i08=0,i09=0,i10=0,i11=0,i12=0,i13=0,i14=0,i15=0,i16=0

// ---------------- KNN scan (R20 proven: quarter per block) ----------------
__global__ __launch_bounds__(256)
void knn_scan(const float* __restrict__ pts, const float* __restrict__ feats,
              u16* __restrict__ fb16, unsigned* __restrict__ kpart) {
#pragma clang fp contract(off)
    __shared__ __align__(16) float4 sp[128];
    const int tid = threadIdx.x;
    {   // feats -> bf16 (grid-stride over 524288 US8 groups)
        const size_t nv = (size_t)NB * NP * CH / 8;
        for (size_t i = (size_t)blockIdx.x * 256 + tid; i < nv; i += (size_t)gridDim.x * 256) {
            float4 f0 = ((const float4*)feats)[i * 2];
            float4 f1 = ((const float4*)feats)[i * 2 + 1];
            ((US8*)fb16)[i] = pack8(f0, f1);
        }
    }
    const int b = blockIdx.x;
    const int n = b >> 3;
    const int ph = (b >> 2) & 1;
    const int qq = b & 3;
    const float* pb = pts + (size_t)n * NP * 2;
    if (tid < 128) {                              // stage this block's quarter
        int i = qq * 128 + tid;
        float x = pb[i * 2], y = pb[i * 2 + 1];
        float r = x * x + y * y;                  // matches np: mul, mul, add
        sp[tid] = make_float4(x, y, r, 0.f);
    }
    __syncthreads();
    const int p = ph * 256 + tid;
    float xp = pb[p * 2], yp = pb[p * 2 + 1];
    float rp = xp * xp + yp * yp;                 // same op order as staging

    KDECL;
    const int q0 = qq << 7;
    for (int t = 0; t < 128; ++t) {
        float4 sq = sp[t];
        float m = xp * sq.x + yp * sq.y;          // einsum inner order
        float d = (rp - 2.0f * m) + sq.z;         // (r - 2m) + r^T order
        unsigned int ub = __float_as_uint(d);
        ub = (ub & 0x80000000u) ? ~ub : (ub | 0x80000000u);
        INS32(ub, (unsigned)(q0 + t));
    }
    unsigned* pp = kpart + (((size_t)(n * NP + p)) * 4 + qq) * 34;
    pp[ 0]=d00; pp[ 1]=d01; pp[ 2]=d02; pp[ 3]=d03; pp[ 4]=d04; pp[ 5]=d05;
    pp[ 6]=d06; pp[ 7]=d07; pp[ 8]=d08; pp[ 9]=d09; pp[10]=d10; pp[11]=d11;
    pp[12]=d12; pp[13]=d13; pp[14]=d14; pp[15]=d15; pp[16]=d16;
    pp[17]=i00; pp[18]=i01; pp[19]=i02; pp[20]=i03; pp[21]=i04; pp[22]=i05;
    pp[23]=i06; pp[24]=i07; pp[25]=i08; pp[26]=i09; pp[27]=i10; pp[28]=i11;
    pp[29]=i12; pp[30]=i13; pp[31]=i14; pp[32]=i15; pp[33]=i16;
}

// ---------------- KNN merge: combine 4 sorted 17-lists -------------------
__global__ __launch_bounds__(256)
void knn_merge(const unsigned* __restrict__ kpart, int* __restrict__ idx) {
    const size_t pt = (size_t)blockIdx.x * 256 + threadIdx.x;
    const unsigned* p0 = kpart + (pt * 4 + 0) * 34;
    unsigned d00=p0[0], d01=p0[1], d02=p0[2], d03=p0[3], d04=p0[4],
             d05=p0[5], d06=p0[6], d07=p0[7], d08=p0[8], d09=p0[9],
             d10=p0[10],d11=p0[11],d12=p0[12],d13=p0[13],d14=p0[14],
             d15=p0[15],d16=p0[16];
    unsigned i00=p0[17],i01=p0[18],i02=p0[19],i03=p0[20],i04=p0[21],
             i05=p0[22],i06=p0[23],i07=p0[24],i08=p0[25],i09=p0[26],
             i10=p0[27],i11=p0[28],i12=p0[29],i13=p0[30],i14=p0[31],
             i15=p0[32],i16=p0[33];
#pragma unroll
    for (int h = 1; h < 4; ++h) {
        const unsigned* p1 = kpart + (pt * 4 + h) * 34;
#pragma unroll
        for (int j = 0; j < 17; ++j) {
            unsigned ub = p1[j], qq = p1[17 + j];
            INS32(ub, qq);
        }
    }
    int* ob = idx + pt * KNN;                     // drop slot 0 (self)
    ob[ 0] = (int)i01;  ob[ 1] = (int)i02;  ob[ 2] = (int)i03;  ob[ 3] = (int)i04;
    ob[ 4] = (int)i05;  ob[ 5] = (int)i06;  ob[ 6] = (int)i07;  ob[ 7] = (int)i08;
    ob[ 8] = (int)i09;  ob[ 9] = (int)i10;  ob[10] = (int)i11;  ob[11] = (int)i12;
    ob[12] = (int)i13;  ob[13] = (int)i14;  ob[14] = (int)i15;  ob[15] = (int)i16;
}

// ---------------- BN finalize ----------------
__global__ void finalize_bn(const float* __restrict__ part, float* __restrict__ bn,
                            const float* g0, const float* b0, const float* g1,
                            const float* b1, const float* g2, const float* b2,
                            const float* scg, const float* scb, int mapA, int mapB) {
    int L = (blockIdx.x == 0) ? mapA : mapB;
    int o = threadIdx.x;
    const float* g = (L == 0) ? g0 : (L == 1) ? g1 : (L == 2) ? g2 : scg;
    const float* b = (L == 0) ? b0 : (L == 1) ? b1 : (L == 2) ? b2 : scb;
    float cnt = (L == 3) ? (float)(NB * NP) : (float)(NB * NP * KNN);
    float s = 0.f, ss = 0.f;
    for (int slot = 0; slot < SLOTS; ++slot) {
        s  += part[((L * SLOTS + slot) * 2 + 0) * 64 + o];
        ss += part[((L * SLOTS + slot) * 2 + 1) * 64 + o];
    }
    float mu  = s / cnt;
    float var = fmaxf(ss / cnt - mu * mu, 0.f);
    float sc  = g[o] * rsqrtf(var + 1e-5f);
    bn[L * 128 + o]      = sc;
    bn[L * 128 + 64 + o] = b[o] - mu * sc;
}

#define MFMA16(a, b, c) __builtin_amdgcn_mfma_f32_16x16x32_bf16(a, b, c, 0, 0, 0)

// ---------------- MFMA MLP phases: deferred-stats persistence --------------
// (R17/R20 structure) + 8x atomic reduction: per-iteration stats shuffles
// accumulate into REGISTERS (A+B groups combined — part slots are arbitrary
// accumulators), flushed ONCE per block at the end. Barrier count unchanged
// (zero). Was ~4M atomics/phase, now ~0.5M.
template <int PHASE>
__global__ __launch_bounds__(256)
void mlp_phase(const u16* __restrict__ fb16, const int* __restrict__ idx,
               const u16* __restrict__ Wn, const u16* __restrict__ Wc,
               const u16* __restrict__ W1b, const u16* __restrict__ W2b,
               const u16* __restrict__ scWb, const float* __restrict__ bn,
               float* __restrict__ part, u16* __restrict__ ybuf,
               float* __restrict__ out) {
    __shared__ char AbA[128 * 128];
    __shared__ char AbB[128 * 128];
    __shared__ char ceA[NPB * 128];
    __shared__ char ceB[NPB * 128];
    __shared__ float scsA[NPB][64];
    __shared__ float scsB[NPB][64];

    const int tid = threadIdx.x;
    const int lane = tid & 63;
    const int w = tid >> 6;
    const int l15 = lane & 15;
    const int g4 = lane >> 4;
    const int r0 = w * 32 + l15, r1 = r0 + 16;
    const int sw0 = (r0 & 7) << 4;
    const int gr_ = w * 32 + (lane >> 1);
    const int gh_ = lane & 1;
    const int gp_ = gr_ >> 4;
    const int gk_ = gr_ & 15;
    const int gsw_ = (gr_ & 7) << 4;
    const int cr_ = 2 * w + ((lane >> 4) & 1);

    float sacc[4] = {0.f, 0.f, 0.f, 0.f};     // deferred layer stats (sum)
    float qacc[4] = {0.f, 0.f, 0.f, 0.f};     // deferred layer stats (ssq)
    float ssac[4] = {0.f, 0.f, 0.f, 0.f};     // P1 shortcut stats (sum)
    float qsac[4] = {0.f, 0.f, 0.f, 0.f};     // P1 shortcut stats (ssq)

    for (int it = 0; it < GPB / 2; ++it) {
        const int gbA = blockIdx.x + it * (2 * GRID_MLP);
        const int gbB = gbA + GRID_MLP;
        const int nA = gbA >> 6, nB = gbB >> 6;
        const size_t rbA = (size_t)nA * NP + (gbA & 63) * NPB;
        const size_t rbB = (size_t)nB * NP + (gbB & 63) * NPB;

        f32x4 accA[2][4], accB[2][4];

        auto layer2 = [&](const u16* Wb) {
#pragma unroll
            for (int ks = 0; ks < 2; ++ks) {
                bf8v aA0 = *(const bf8v*)(AbA + r0 * 128 + ((ks * 64 + g4 * 16) ^ sw0));
                bf8v aA1 = *(const bf8v*)(AbA + r1 * 128 + ((ks * 64 + g4 * 16) ^ sw0));
                bf8v aB0 = *(const bf8v*)(AbB + r0 * 128 + ((ks * 64 + g4 * 16) ^ sw0));
                bf8v aB1 = *(const bf8v*)(AbB + r1 * 128 + ((ks * 64 + g4 * 16) ^ sw0));
#pragma unroll
                for (int ct = 0; ct < 4; ++ct) {
                    bf8v b = *(const bf8v*)((const char*)Wb + (ct * 16 + l15) * 128 + ks * 64 + g4 * 16);
                    accA[0][ct] = MFMA16(aA0, b, accA[0][ct]);
                    accA[1][ct] = MFMA16(aA1, b, accA[1][ct]);
                    accB[0][ct] = MFMA16(aB0, b, accB[0][ct]);
                    accB[1][ct] = MFMA16(aB1, b, accB[1][ct]);
                }
            }
        };
        auto layerC2 = [&](const u16* Wb) {
#pragma unroll
            for (int ks = 0; ks < 2; ++ks) {
                bf8v cA0 = *(const bf8v*)(ceA + (2 * w) * 128 + ks * 64 + g4 * 16);
                bf8v cA1 = *(const bf8v*)(ceA + (2 * w + 1) * 128 + ks * 64 + g4 * 16);
                bf8v cB0 = *(const bf8v*)(ceB + (2 * w) * 128 + ks * 64 + g4 * 16);
                bf8v cB1 = *(const bf8v*)(ceB + (2 * w + 1) * 128 + ks * 64 + g4 * 16);
#pragma unroll
                for (int ct = 0; ct < 4; ++ct) {
                    bf8v b = *(const bf8v*)((const char*)Wb + (ct * 16 + l15) * 128 + ks * 64 + g4 * 16);
                    accA[0][ct] = MFMA16(cA0, b, accA[0][ct]);
                    accA[1][ct] = MFMA16(cA1, b, accA[1][ct]);
                    accB[0][ct] = MFMA16(cB0, b, accB[0][ct]);
                    accB[1][ct] = MFMA16(cB1, b, accB[1][ct]);
                }
            }
        };
        auto store_acc = [&]() {
            u16* ya = ybuf + ((size_t)gbA * 256 + tid) * 32;
            u16* yc = ybuf + ((size_t)gbB * 256 + tid) * 32;
#pragma unroll
            for (int c4 = 0; c4 < 4; ++c4) {
                US8 ua, ub;
#pragma unroll
                for (int e = 0; e < 8; ++e) {
                    int i = c4 * 8 + e;
                    ua.v[e] = f2bf(accA[i >> 4][(i >> 2) & 3][i & 3]);
                    ub.v[e] = f2bf(accB[i >> 4][(i >> 2) & 3][i & 3]);
                }
                ((US8*)ya)[c4] = ua;
                ((US8*)yc)[c4] = ub;
            }
        };
        auto load_acc = [&]() {
            const u16* ya = ybuf + ((size_t)gbA * 256 + tid) * 32;
            const u16* yc = ybuf + ((size_t)gbB * 256 + tid) * 32;
#pragma unroll
            for (int c4 = 0; c4 < 4; ++c4) {
                US8 ua = ((const US8*)ya)[c4];
                US8 ub = ((const US8*)yc)[c4];
#pragma unroll
                for (int e = 0; e < 8; ++e) {
                    int i = c4 * 8 + e;
                    accA[i >> 4][(i >> 2) & 3][i & 3] = bf2f(ua.v[e]);
                    accB[i >> 4][(i >> 2) & 3][i & 3] = bf2f(ub.v[e]);
                }
            }
        };
        auto load_centers = [&]() {
            if (lane < 32) {
                ((uint2*)(ceA + cr_ * 128))[lane & 15] =
                    ((const uint2*)(fb16 + (rbA + cr_) * CH))[lane & 15];
                ((uint2*)(ceB + cr_ * 128))[lane & 15] =
                    ((const uint2*)(fb16 + (rbB + cr_) * CH))[lane & 15];
            }
        };
        // shuffle-reduce and ACCUMULATE into registers (A+B combined)
        auto stats_acc = [&]() {
#pragma unroll
            for (int ct = 0; ct < 4; ++ct) {
                float a = 0.f, b = 0.f, c = 0.f, d = 0.f;
#pragma unroll
                for (int rt = 0; rt < 2; ++rt)
#pragma unroll
                    for (int j = 0; j < 4; ++j) {
                        float vA = accA[rt][ct][j]; a += vA; b += vA * vA;
                        float vB = accB[rt][ct][j]; c += vB; d += vB * vB;
                    }
                a += c; b += d;
                a += __shfl_xor(a, 16); a += __shfl_xor(a, 32);
                b += __shfl_xor(b, 16); b += __shfl_xor(b, 32);
                sacc[ct] += a;
                qacc[ct] += b;
            }
        };
        auto bnwb2 = [&](int L) {
#pragma unroll
            for (int ct = 0; ct < 4; ++ct) {
                int ch = ct * 16 + l15;
                float sc = bn[L * 128 + ch], sh = bn[L * 128 + 64 + ch];
#pragma unroll
                for (int rt = 0; rt < 2; ++rt)
#pragma unroll
                    for (int j = 0; j < 4; ++j) {
                        int gr = w * 32 + rt * 16 + g4 * 4 + j;
                        int off = gr * 128 + ((ch * 2) ^ ((gr & 7) << 4));
                        float vA = fmaxf(fmaf(accA[rt][ct][j], sc, sh), 0.f);
                        float vB = fmaxf(fmaf(accB[rt][ct][j], sc, sh), 0.f);
                        *(u16*)(AbA + off) = f2bf(vA);
                        *(u16*)(AbB + off) = f2bf(vB);
                        accA[rt][ct][j] = 0.f;
                        accB[rt][ct][j] = 0.f;
                    }
            }
        };

        if (PHASE == 1) {
            int srcA = idx[(rbA + gp_) * KNN + gk_];
            int srcB = idx[(rbB + gp_) * KNN + gk_];
            const US8* gA = (const US8*)(fb16 + ((size_t)nA * NP + srcA) * CH + gh_ * 32);
            const US8* gB = (const US8*)(fb16 + ((size_t)nB * NP + srcB) * CH + gh_ * 32);
            US8 aq0 = gA[0], aq1 = gA[1], aq2 = gA[2], aq3 = gA[3];
            US8 bq0 = gB[0], bq1 = gB[1], bq2 = gB[2], bq3 = gB[3];
            uint2 acen = ((const uint2*)(fb16 + (rbA + cr_) * CH))[lane & 15];
            uint2 bcen = ((const uint2*)(fb16 + (rbB + cr_) * CH))[lane & 15];
            char* ra = AbA + gr_ * 128;
            *(US8*)(ra + ((gh_ * 64 +  0) ^ gsw_)) = aq0;
            *(US8*)(ra + ((gh_ * 64 + 16) ^ gsw_)) = aq1;
            *(US8*)(ra + ((gh_ * 64 + 32) ^ gsw_)) = aq2;
            *(US8*)(ra + ((gh_ * 64 + 48) ^ gsw_)) = aq3;
            char* rb = AbB + gr_ * 128;
            *(US8*)(rb + ((gh_ * 64 +  0) ^ gsw_)) = bq0;
            *(US8*)(rb + ((gh_ * 64 + 16) ^ gsw_)) = bq1;
            *(US8*)(rb + ((gh_ * 64 + 32) ^ gsw_)) = bq2;
            *(US8*)(rb + ((gh_ * 64 + 48) ^ gsw_)) = bq3;
            if (lane < 32) {
                ((uint2*)(ceA + cr_ * 128))[lane & 15] = acen;
                ((uint2*)(ceB + cr_ * 128))[lane & 15] = bcen;
            }
#pragma unroll
            for (int rt = 0; rt < 2; ++rt)
#pragma unroll
                for (int ct = 0; ct < 4; ++ct) {
                    accA[rt][ct] = (f32x4){0.f, 0.f, 0.f, 0.f};
                    accB[rt][ct] = (f32x4){0.f, 0.f, 0.f, 0.f};
                }
            layer2(Wn);
            layerC2(Wc);
            store_acc();
            stats_acc();
            // shortcut MFMA + masked stats accumulate (valid: g4==0, j<2)
            f32x4 shA[4], shB[4];
#pragma unroll
            for (int ct = 0; ct < 4; ++ct) {
                shA[ct] = (f32x4){0.f, 0.f, 0.f, 0.f};
                shB[ct] = (f32x4){0.f, 0.f, 0.f, 0.f};
            }
#pragma unroll
            for (int ks = 0; ks < 2; ++ks) {
                int arow = (l15 < 2) ? (2 * w + l15) : (2 * w);
                bf8v aA = *(const bf8v*)(ceA + arow * 128 + ks * 64 + g4 * 16);
                bf8v aB = *(const bf8v*)(ceB + arow * 128 + ks * 64 + g4 * 16);
#pragma unroll
                for (int ct = 0; ct < 4; ++ct) {
                    bf8v b = *(const bf8v*)((const char*)scWb + (ct * 16 + l15) * 128 + ks * 64 + g4 * 16);
                    shA[ct] = MFMA16(aA, b, shA[ct]);
                    shB[ct] = MFMA16(aB, b, shB[ct]);
                }
            }
#pragma unroll
            for (int ct = 0; ct < 4; ++ct) {
                float uA = (g4 == 0) ? shA[ct][0] : 0.f;
                float vA = (g4 == 0) ? shA[ct][1] : 0.f;
                float uB = (g4 == 0) ? shB[ct][0] : 0.f;
                float vB = (g4 == 0) ? shB[ct][1] : 0.f;
                float a = uA + vA + uB + vB;
                float b = uA * uA + vA * vA + uB * uB + vB * vB;
                a += __shfl_xor(a, 16); a += __shfl_xor(a, 32);
                b += __shfl_xor(b, 16); b += __shfl_xor(b, 32);
                ssac[ct] += a;
                qsac[ct] += b;
            }
            continue;
        }

        if (PHASE == 2) {
            load_acc();
            bnwb2(0);
            layer2(W1b);
            store_acc();
            stats_acc();
            continue;
        }
        if (PHASE == 3) {
            load_acc();
            bnwb2(1);
            layer2(W2b);
            store_acc();
            stats_acc();
            continue;
        }

        load_acc();
        load_centers();
        {
            float m0A[4], m1A[4], m0B[4], m1B[4];
#pragma unroll
            for (int ct = 0; ct < 4; ++ct) {
                int ch = ct * 16 + l15;
                float sc = bn[2 * 128 + ch], sh = bn[2 * 128 + 64 + ch];
                float ma = 0.f, mb = 0.f, mc = 0.f, md = 0.f;
#pragma unroll
                for (int j = 0; j < 4; ++j) {
                    ma += fmaxf(fmaf(accA[0][ct][j], sc, sh), 0.f);
                    mb += fmaxf(fmaf(accA[1][ct][j], sc, sh), 0.f);
                    mc += fmaxf(fmaf(accB[0][ct][j], sc, sh), 0.f);
                    md += fmaxf(fmaf(accB[1][ct][j], sc, sh), 0.f);
                }
                ma += __shfl_xor(ma, 16); ma += __shfl_xor(ma, 32);
                mb += __shfl_xor(mb, 16); mb += __shfl_xor(mb, 32);
                mc += __shfl_xor(mc, 16); mc += __shfl_xor(mc, 32);
                md += __shfl_xor(md, 16); md += __shfl_xor(md, 32);
                m0A[ct] = ma; m1A[ct] = mb; m0B[ct] = mc; m1B[ct] = md;
            }
            f32x4 shA[4], shB[4];
#pragma unroll
            for (int ct = 0; ct < 4; ++ct) {
                shA[ct] = (f32x4){0.f, 0.f, 0.f, 0.f};
                shB[ct] = (f32x4){0.f, 0.f, 0.f, 0.f};
            }
#pragma unroll
            for (int ks = 0; ks < 2; ++ks) {
                int arow = (l15 < 2) ? (2 * w + l15) : (2 * w);
                bf8v aA = *(const bf8v*)(ceA + arow * 128 + ks * 64 + g4 * 16);
                bf8v aB = *(const bf8v*)(ceB + arow * 128 + ks * 64 + g4 * 16);
#pragma unroll
                for (int ct = 0; ct < 4; ++ct) {
                    bf8v b = *(const bf8v*)((const char*)scWb + (ct * 16 + l15) * 128 + ks * 64 + g4 * 16);
                    shA[ct] = MFMA16(aA, b, shA[ct]);
                    shB[ct] = MFMA16(aB, b, shB[ct]);
                }
            }
            if (g4 == 0) {
#pragma unroll
                for (int ct = 0; ct < 4; ++ct) {
                    int ch = ct * 16 + l15;
                    float s3 = bn[3 * 128 + ch], h3 = bn[3 * 128 + 64 + ch];
                    scsA[2 * w + 0][ch] = fmaxf(fmaf(shA[ct][0], s3, h3), 0.f);
                    scsA[2 * w + 1][ch] = fmaxf(fmaf(shA[ct][1], s3, h3), 0.f);
                    scsB[2 * w + 0][ch] = fmaxf(fmaf(shB[ct][0], s3, h3), 0.f);
                    scsB[2 * w + 1][ch] = fmaxf(fmaf(shB[ct][1], s3, h3), 0.f);
                }
            }
            int ph = g4 >> 1;
            int p = 2 * w + ph;
            int cb2 = g4 & 1;
            int ch0 = (cb2 * 2) * 16 + l15;
            int ch1 = ch0 + 16;
            {
                float lo0 = cb2 ? m0A[2] : m0A[0], hi0 = cb2 ? m1A[2] : m1A[0];
                float lo1 = cb2 ? m0A[3] : m0A[1], hi1 = cb2 ? m1A[3] : m1A[1];
                float mva = ph ? hi0 : lo0;
                float mvb = ph ? hi1 : lo1;
                float* ob = out + (rbA + p) * CH;
                ob[ch0] = mva * 0.0625f + scsA[p][ch0];
                ob[ch1] = mvb * 0.0625f + scsA[p][ch1];
            }
            {
                float lo0 = cb2 ? m0B[2] : m0B[0], hi0 = cb2 ? m1B[2] : m1B[0];
                float lo1 = cb2 ? m0B[3] : m0B[1], hi1 = cb2 ? m1B[3] : m1B[1];
                float mva = ph ? hi0 : lo0;
                float mvb = ph ? hi1 : lo1;
                float* ob = out + (rbB + p) * CH;
                ob[ch0] = mva * 0.0625f + scsB[p][ch0];
                ob[ch1] = mvb * 0.0625f + scsB[p][ch1];
            }
        }
    }

    // ---- deferred stats flush: once per block, barrier-free ----
    if (PHASE != 4 && lane < 16) {
        const int L = (PHASE == 1) ? 0 : (PHASE == 2) ? 1 : 2;
        const int slot = blockIdx.x & (SLOTS - 1);
#pragma unroll
        for (int ct = 0; ct < 4; ++ct) {
            int ch = ct * 16 + lane;
            atomicAdd(&part[((L * SLOTS + slot) * 2 + 0) * 64 + ch], sacc[ct]);
            atomicAdd(&part[((L * SLOTS + slot) * 2 + 1) * 64 + ch], qacc[ct]);
        }
        if (PHASE == 1) {
#pragma unroll
            for (int ct = 0; ct < 4; ++ct) {
                int ch = ct * 16 + lane;
                atomicAdd(&part[((3 * SLOTS + slot) * 2 + 0) * 64 + ch], ssac[ct]);
                atomicAdd(&part[((3 * SLOTS + slot) * 2 + 1) * 64 + ch], qsac[ct]);
            }
        }
    }
}

extern "C" void kernel_launch(void* const* d_in, const int* in_sizes, int n_in,
                              void* d_out, int out_size, void* d_ws, size_t ws_size,
                              hipStream_t stream) {
    const float* points = (const float*)d_in[0];
    const float* feats  = (const float*)d_in[1];
    const float* W0  = (const float*)d_in[2];
    const float* g0  = (const float*)d_in[3];
    const float* b0  = (const float*)d_in[4];
    const float* W1  = (const float*)d_in[5];
    const float* g1  = (const float*)d_in[6];
    const float* b1  = (const float*)d_in[7];
    const float* W2  = (const float*)d_in[8];
    const float* g2  = (const float*)d_in[9];
    const float* b2  = (const float*)d_in[10];
    const float* scW = (const float*)d_in[11];
    const float* scg = (const float*)d_in[12];
    const float* scb = (const float*)d_in[13];
    float* out = (float*)d_out;

    char* ws = (char*)d_ws;
    int*   idx  = (int*)(ws + OFF_IDX);
    float* part = (float*)(ws + OFF_PART);
    float* bn   = (float*)(ws + OFF_BN);
    u16*   Wn   = (u16*)(ws + OFF_WN);
    u16*   Wc   = (u16*)(ws + OFF_WC);
    u16*   W1b  = (u16*)(ws + OFF_W1B);
    u16*   W2b  = (u16*)(ws + OFF_W2B);
    u16*   scWb = (u16*)(ws + OFF_SCWB);
    u16*   fb16 = (u16*)(ws + OFF_FB16);
    u16*   y1   = (u16*)(ws + OFF_Y1);
    unsigned* kp = (unsigned*)(ws + OFF_KPART);   // overlaps y1 (dead until P1)

    hipMemsetAsync(part, 0, PART_BYTES, stream);
    prep_weights<<<16, 256, 0, stream>>>(W0, W1, W2, scW, Wn, Wc, W1b, W2b, scWb);
    knn_scan<<<NB * 8, 256, 0, stream>>>(points, feats, fb16, kp);
    knn_merge<<<NB * 2, 256, 0, stream>>>(kp, idx);

    mlp_phase<1><<<GRID_MLP, 256, 0, stream>>>(fb16, idx, Wn, Wc, W1b, W2b, scWb, bn, part, y1, out);
    finalize_bn<<<2, 64, 0, stream>>>(part, bn, g0, b0, g1, b1, g2, b2, scg, scb, 0, 3);
    mlp_phase<2><<<GRID_MLP, 256, 0, stream>>>(fb16, idx, Wn, Wc, W1b, W2b, scWb, bn, part, y1, out);
    finalize_bn<<<1, 64, 0, stream>>>(part, bn, g0, b0, g1, b1, g2, b2, scg, scb, 1, 1);
    mlp_phase<3><<<GRID_MLP, 256, 0, stream>>>(fb16, idx, Wn, Wc, W1b, W2b, scWb, bn, part, y1, out);
    finalize_bn<<<1, 64, 0, stream>>>(part, bn, g0, b0, g1, b1, g2, b2, scg, scb, 2, 2);
    mlp_phase<4><<<GRID_MLP, 256, 0, stream>>>(fb16, idx, Wn, Wc, W1b, W2b, scWb, bn, part, y1, out);
}